// Round 1
// baseline (59190.021 us; speedup 1.0000x reference)
//
#include <hip/hip_runtime.h>
#include <math.h>

#define NWG 64
#define TPB 1024

constexpr int Bn = 16, Sn = 128, Vn = 32000, DMn = 1024, DSn = 512;
constexpr float DECAYc = 0.6065306597126334f;  // exp(-1/tau), tau=2
constexpr float THRc = 1.0f, EPSc = 1e-5f;

// ---- workspace byte offsets ----
constexpr size_t OF_FLAGS  = 0;                                   // 64 flags * 64B
constexpr size_t OF_STATES = 4096;                                // [2][16][512] f32
constexpr size_t OF_ENCM   = OF_STATES + (size_t)2*16*512*4;      // [16][1024]
constexpr size_t OF_GENM   = OF_ENCM   + (size_t)16*1024*4;       // [2][16][1024]
constexpr size_t OF_INFM   = OF_GENM   + (size_t)2*16*1024*4;     // [2][16][512]
constexpr size_t OF_ERR0   = OF_INFM   + (size_t)2*16*512*4;      // [16][1024]
constexpr size_t OF_ERR1   = OF_ERR0   + (size_t)16*1024*4;       // [16][1024]
constexpr size_t OF_HS     = OF_ERR1   + (size_t)16*1024*4;       // [128][16][512]
constexpr size_t INIT_BYTES = OF_ERR0;  // zero flags + states + all LIF mems

struct SP {
  const int* ids; const float* emb;
  const float* W_enc; const float* b_enc;
  const float* ln_s_g; const float* ln_s_b;
  const float* Wg; const float* bg;
  const float* ln_e_g; const float* ln_e_b;
  const float* Wi; const float* bi;
};

// device-wide barrier: each WG publishes its epoch; wave 0 polls all flags.
__device__ __forceinline__ void gbar(int* flags, int wg, int tid, int epoch) {
  __threadfence();                 // release: drain my writes to device scope
  __syncthreads();
  if (tid == 0)
    __hip_atomic_store(flags + wg*16, epoch, __ATOMIC_RELEASE, __HIP_MEMORY_SCOPE_AGENT);
  if (tid < NWG) {
    while (__hip_atomic_load(flags + tid*16, __ATOMIC_RELAXED, __HIP_MEMORY_SCOPE_AGENT) < epoch) { }
    __threadfence();               // acquire: invalidate so subsequent reads are fresh
  }
  __syncthreads();
}

// One fused step: [16,K] (gather or LayerNorm) @ W[K,O] + bias -> LIF -> outputs.
// MODE 0 = encoder (X = embedding rows), 1 = generative (X = ln(states[j])),
// MODE 2 = inference (X = ln(error)).
template<int K, int O, int MODE>
__device__ __forceinline__ void step_fn(
    const float* __restrict__ Wmat, const float* __restrict__ bias,
    const float* __restrict__ lng, const float* __restrict__ lnb,
    const float* __restrict__ src, const int* __restrict__ ids, int s,
    float* __restrict__ mem,
    const float* __restrict__ errr, float* __restrict__ errw,
    float* __restrict__ stw, float* __restrict__ hsw,
    float* X, int wg, int tid)
{
  const bool active = (wg * 16) < O;   // O/16 workgroups needed
  // ---- Phase X: stage input rows into LDS (and LayerNorm in place) ----
  if (active) {
    if (MODE == 0) {
      for (int idx = tid; idx < 16*(K/4); idx += TPB) {
        int b = idx / (K/4), k4 = idx % (K/4);
        int row = ids[b*Sn + s];
        ((float4*)X)[idx] = ((const float4*)(src + (size_t)row*DMn))[k4];
      }
    } else {
      for (int idx = tid; idx < 16*(K/4); idx += TPB)
        ((float4*)X)[idx] = ((const float4*)src)[idx];
      __syncthreads();
      // wave w owns row w (16 waves, 16 rows)
      const int w = tid >> 6, l = tid & 63;
      float* row = X + w*K;
      float s1 = 0.f;
      for (int k = l; k < K; k += 64) s1 += row[k];
      #pragma unroll
      for (int off = 32; off; off >>= 1) s1 += __shfl_xor(s1, off);
      const float mean = s1 * (1.0f/K);
      float s2 = 0.f;
      for (int k = l; k < K; k += 64) { float d = row[k] - mean; s2 += d*d; }
      #pragma unroll
      for (int off = 32; off; off >>= 1) s2 += __shfl_xor(s2, off);
      const float rstd = 1.0f / sqrtf(s2 * (1.0f/K) + EPSc);
      for (int k = l; k < K; k += 64)
        row[k] = (row[k] - mean) * rstd * lng[k] + lnb[k];
    }
  }
  __syncthreads();
  // ---- Phase G: GEMM. thread = (o_l in 0..15, kc in 0..63); all 16 b in regs ----
  constexpr int KC = K / 64;
  float acc[16];
  if (active) {
    const int o_l = tid & 15, kc = tid >> 4;
    const int o = wg*16 + o_l;
    float wr[KC];
    const float* wp = Wmat + (size_t)(kc*KC)*O + o;
    #pragma unroll
    for (int i = 0; i < KC; i++) wr[i] = wp[(size_t)i * O];
    #pragma unroll
    for (int b = 0; b < 16; b++) acc[b] = 0.f;
    #pragma unroll 2
    for (int b = 0; b < 16; b++) {
      const float4* xr = (const float4*)(X + b*K + kc*KC);
      float t0=0.f, t1=0.f, t2=0.f, t3=0.f;
      #pragma unroll
      for (int q = 0; q < KC/4; q++) {
        float4 xv = xr[q];
        t0 += xv.x * wr[4*q+0];
        t1 += xv.y * wr[4*q+1];
        t2 += xv.z * wr[4*q+2];
        t3 += xv.w * wr[4*q+3];
      }
      acc[b] = (t0+t1) + (t2+t3);
    }
    // in-wave reduce over the 4 kc values living in this wave
    #pragma unroll
    for (int b = 0; b < 16; b++) {
      acc[b] += __shfl_xor(acc[b], 16);
      acc[b] += __shfl_xor(acc[b], 32);
    }
  }
  __syncthreads();                 // X reads done; safe to alias X as pbuf
  float* pbuf = X;                 // [16 wavegrp][16 o_l][16 b]
  if (active && (tid & 63) < 16) {
    const int w = tid >> 6, o_l = tid & 15;
    #pragma unroll
    for (int b = 0; b < 16; b++) pbuf[(w*16 + o_l)*16 + b] = acc[b];
  }
  __syncthreads();
  // ---- Phase R: final reduce + bias + LIF + output writes ----
  if (active && tid < 256) {
    const int o_l = tid & 15, b = tid >> 4;
    const int o = wg*16 + o_l;
    float v = 0.f;
    #pragma unroll
    for (int w = 0; w < 16; w++) v += pbuf[(w*16 + o_l)*16 + b];
    v += bias[o];
    float mt = mem[b*O + o] * DECAYc + v;
    float spk = (mt >= THRc) ? 1.f : 0.f;
    mem[b*O + o] = mt * (1.f - spk);
    if (MODE == 0) {
      errw[b*DMn + o] = spk;                       // bottom = spike
    } else if (MODE == 1) {
      errw[b*DMn + o] = errr[b*DMn + o] - spk;     // error = bottom - pred
    } else {
      float ns = stw[b*DSn + o] + spk;             // states[j] += upd
      stw[b*DSn + o] = ns;
      if (hsw) hsw[b*DSn + o] = ns;                // capture h_s at (t=3,j=1)
    }
  }
}

__global__ void __launch_bounds__(TPB) snn_scan(SP p, char* __restrict__ ws)
{
  __shared__ float X[16*1024];     // 64 KiB, reused each step (pbuf aliases it)
  const int wg = blockIdx.x, tid = threadIdx.x;
  int*   flags  = (int*)  (ws + OF_FLAGS);
  float* states = (float*)(ws + OF_STATES);
  float* encm   = (float*)(ws + OF_ENCM);
  float* genm   = (float*)(ws + OF_GENM);
  float* infm   = (float*)(ws + OF_INFM);
  float* e0     = (float*)(ws + OF_ERR0);
  float* e1     = (float*)(ws + OF_ERR1);
  float* hs     = (float*)(ws + OF_HS);

  int epoch = 0;
  for (int s = 0; s < Sn; s++) {
    // encoder: emb @ W_enc + b_enc -> LIF -> bottom (err buf 0)
    step_fn<1024,1024,0>(p.W_enc, p.b_enc, nullptr, nullptr, p.emb, p.ids, s,
                         encm, nullptr, e0, nullptr, nullptr, X, wg, tid);
    gbar(flags, wg, tid, ++epoch);
    int pp = 0;
    for (int it = 0; it < 8; it++) {     // it = t*2 + j
      const int j = it & 1;
      // generative: ln(states[j]) @ Wg[j] -> LIF -> pred; error = bottom - pred
      step_fn<512,1024,1>(p.Wg + (size_t)j*512*1024, p.bg + j*1024,
                          p.ln_s_g + j*512, p.ln_s_b + j*512,
                          states + j*16*512, nullptr, 0,
                          genm + j*16*1024,
                          pp ? e1 : e0, pp ? e0 : e1,
                          nullptr, nullptr, X, wg, tid);
      gbar(flags, wg, tid, ++epoch);
      pp ^= 1;
      // inference: ln(error) @ Wi[j] -> LIF -> upd; states[j] += upd
      step_fn<1024,512,2>(p.Wi + (size_t)j*1024*512, p.bi + j*512,
                          p.ln_e_g + j*1024, p.ln_e_b + j*1024,
                          pp ? e1 : e0, nullptr, 0,
                          infm + j*16*512,
                          nullptr, nullptr,
                          states + j*16*512,
                          (it == 7) ? (hs + (size_t)s*16*512) : nullptr,
                          X, wg, tid);
      gbar(flags, wg, tid, ++epoch);
    }
  }
}

// logits = hs @ W_out + b_out, fp32, 128x128 tile, 8x8 microtile
__global__ void __launch_bounds__(256) out_gemm(
    const float* __restrict__ hs, const float* __restrict__ Wo,
    const float* __restrict__ bo, float* __restrict__ out)
{
  __shared__ float As[32][128];    // [k][m]
  __shared__ float Bs[32][128];    // [k][n]
  const int tid = threadIdx.x;
  const int ntile = blockIdx.x * 128;
  const int mtile = blockIdx.y * 128;
  const int tx = tid & 15, ty = tid >> 4;
  float acc[8][8];
  #pragma unroll
  for (int i = 0; i < 8; i++)
    #pragma unroll
    for (int q = 0; q < 8; q++) acc[i][q] = 0.f;

  for (int kb = 0; kb < 16; kb++) {
    #pragma unroll
    for (int r = 0; r < 4; r++) {
      int idx = tid + r*256;             // 1024 float4 slots: 128 m x 8 kq
      int m = idx >> 3, kq = idx & 7;
      float4 a = *(const float4*)(hs + (size_t)(mtile+m)*512 + kb*32 + kq*4);
      As[kq*4+0][m] = a.x; As[kq*4+1][m] = a.y;
      As[kq*4+2][m] = a.z; As[kq*4+3][m] = a.w;
    }
    #pragma unroll
    for (int r = 0; r < 4; r++) {
      int idx = tid + r*256;             // 32 k x 32 nq
      int k = idx >> 5, nq = idx & 31;
      *(float4*)(&Bs[k][nq*4]) =
          *(const float4*)(Wo + (size_t)(kb*32+k)*Vn + ntile + nq*4);
    }
    __syncthreads();
    #pragma unroll
    for (int k = 0; k < 32; k++) {
      float4 a0 = *(float4*)(&As[k][ty*8]);
      float4 a1 = *(float4*)(&As[k][ty*8+4]);
      float4 b0 = *(float4*)(&Bs[k][tx*8]);
      float4 b1 = *(float4*)(&Bs[k][tx*8+4]);
      float av[8] = {a0.x,a0.y,a0.z,a0.w,a1.x,a1.y,a1.z,a1.w};
      float bv[8] = {b0.x,b0.y,b0.z,b0.w,b1.x,b1.y,b1.z,b1.w};
      #pragma unroll
      for (int i = 0; i < 8; i++)
        #pragma unroll
        for (int q = 0; q < 8; q++) acc[i][q] += av[i]*bv[q];
    }
    __syncthreads();
  }
  const float* bop = bo + ntile + tx*8;
  float4 bv0 = *(const float4*)bop;
  float4 bv1 = *(const float4*)(bop + 4);
  #pragma unroll
  for (int i = 0; i < 8; i++) {
    int m = mtile + ty*8 + i;            // m = s*16 + b
    float* op = out + ((size_t)(m & 15)*Sn + (m >> 4))*Vn + ntile + tx*8;
    float4 v0 = make_float4(acc[i][0]+bv0.x, acc[i][1]+bv0.y,
                            acc[i][2]+bv0.z, acc[i][3]+bv0.w);
    float4 v1 = make_float4(acc[i][4]+bv1.x, acc[i][5]+bv1.y,
                            acc[i][6]+bv1.z, acc[i][7]+bv1.w);
    *(float4*)op = v0;
    *(float4*)(op + 4) = v1;
  }
}

extern "C" void kernel_launch(void* const* d_in, const int* in_sizes, int n_in,
                              void* d_out, int out_size, void* d_ws, size_t ws_size,
                              hipStream_t stream) {
  (void)in_sizes; (void)n_in; (void)out_size; (void)ws_size;
  SP p;
  p.ids    = (const int*)  d_in[0];
  p.emb    = (const float*)d_in[1];
  p.W_enc  = (const float*)d_in[2];
  p.b_enc  = (const float*)d_in[3];
  p.ln_s_g = (const float*)d_in[4];
  p.ln_s_b = (const float*)d_in[5];
  p.Wg     = (const float*)d_in[6];
  p.bg     = (const float*)d_in[7];
  p.ln_e_g = (const float*)d_in[8];
  p.ln_e_b = (const float*)d_in[9];
  p.Wi     = (const float*)d_in[10];
  p.bi     = (const float*)d_in[11];
  const float* Wo = (const float*)d_in[12];
  const float* bo = (const float*)d_in[13];

  char* ws = (char*)d_ws;
  hipMemsetAsync(ws, 0, INIT_BYTES, stream);   // flags + carry state = 0
  hipLaunchKernelGGL(snn_scan, dim3(NWG), dim3(TPB), 0, stream, p, ws);
  float* hs = (float*)(ws + OF_HS);
  hipLaunchKernelGGL(out_gemm, dim3(Vn/128, 2048/128), dim3(256), 0, stream,
                     hs, Wo, bo, (float*)d_out);
}

// Round 2
// 29375.415 us; speedup vs baseline: 2.0150x; 2.0150x over previous
//
#include <hip/hip_runtime.h>
#include <math.h>

#define NWG 64
#define TPB 1024

constexpr int Bn = 16, Sn = 128, Vn = 32000, DMn = 1024, DSn = 512;
constexpr float DECAYc = 0.6065306597126334f;  // exp(-1/tau), tau=2
constexpr float THRc = 1.0f, EPSc = 1e-5f;

// ---- workspace byte offsets ----
constexpr size_t OF_FLAGS  = 0;                                   // 64 flags * 128B
constexpr size_t OF_STATES = 8192;                                // [2][16][512] f32
constexpr size_t OF_ENCM   = OF_STATES + (size_t)2*16*512*4;      // [16][1024]
constexpr size_t OF_GENM   = OF_ENCM   + (size_t)16*1024*4;       // [2][16][1024]
constexpr size_t OF_INFM   = OF_GENM   + (size_t)2*16*1024*4;     // [2][16][512]
constexpr size_t OF_ERR0   = OF_INFM   + (size_t)2*16*512*4;      // [16][1024]
constexpr size_t OF_ERR1   = OF_ERR0   + (size_t)16*1024*4;       // [16][1024]
constexpr size_t OF_HS     = OF_ERR1   + (size_t)16*1024*4;       // [128][16][512]
constexpr size_t INIT_BYTES = OF_ERR0;  // zero flags + states + all LIF mems

struct SP {
  const int* ids; const float* emb;
  const float* W_enc; const float* b_enc;
  const float* ln_s_g; const float* ln_s_b;
  const float* Wg; const float* bg;
  const float* ln_e_g; const float* ln_e_b;
  const float* Wi; const float* bi;
};

// L2-bypassing (device-coherent, write-through to LLC) access helpers.
// These compile to global_load/store_dword with sc0 sc1 — no fences needed.
__device__ __forceinline__ float ld_cg(const float* p) {
  return __hip_atomic_load(p, __ATOMIC_RELAXED, __HIP_MEMORY_SCOPE_AGENT);
}
__device__ __forceinline__ void st_cg(float* p, float v) {
  __hip_atomic_store(p, v, __ATOMIC_RELAXED, __HIP_MEMORY_SCOPE_AGENT);
}

// device-wide barrier with NO cache maintenance: all cross-WG data is
// write-through (sc0 sc1), so draining vmcnt suffices before signaling.
__device__ __forceinline__ void gbar(int* flags, int wg, int tid, int epoch) {
  asm volatile("s_waitcnt vmcnt(0)" ::: "memory");   // my wave's WT stores at LLC
  __syncthreads();                                   // all waves drained
  if (tid == 0)
    __hip_atomic_store(flags + wg*32, epoch, __ATOMIC_RELAXED, __HIP_MEMORY_SCOPE_AGENT);
  if (tid < NWG) {
    while (__hip_atomic_load(flags + tid*32, __ATOMIC_RELAXED, __HIP_MEMORY_SCOPE_AGENT) < epoch) { }
  }
  asm volatile("" ::: "memory");                     // no hoisting of data loads
  __syncthreads();
}

// One fused step: [16,K] (gather or LayerNorm) @ W[K,O] + bias -> LIF -> outputs.
// MODE 0 = encoder (X = embedding rows), 1 = generative (X = ln(states[j])),
// MODE 2 = inference (X = ln(error)).
template<int K, int O, int MODE>
__device__ __forceinline__ void step_fn(
    const float* __restrict__ Wmat, const float* __restrict__ bias,
    const float* __restrict__ lng, const float* __restrict__ lnb,
    const float* __restrict__ src, const int* __restrict__ ids, int s,
    float* __restrict__ mem,
    const float* __restrict__ errr, float* __restrict__ errw,
    float* __restrict__ stw, float* __restrict__ hsw,
    float* X, int wg, int tid)
{
  const bool active = (wg * 16) < O;   // O/16 workgroups needed
  // ---- Phase X: stage input rows into LDS (and LayerNorm in place) ----
  if (active) {
    if (MODE == 0) {
      for (int idx = tid; idx < 16*(K/4); idx += TPB) {
        int b = idx / (K/4), k4 = idx % (K/4);
        int row = ids[b*Sn + s];
        ((float4*)X)[idx] = ((const float4*)(src + (size_t)row*DMn))[k4];
      }
    } else {
      constexpr int NV = 16*K/TPB;
      #pragma unroll
      for (int r = 0; r < NV; r++) {
        int idx = tid + r*TPB;
        X[idx] = ld_cg(src + idx);     // coherent read (writer bypassed L2)
      }
      __syncthreads();
      // wave w owns row w (16 waves, 16 rows)
      const int w = tid >> 6, l = tid & 63;
      float* row = X + w*K;
      float s1 = 0.f;
      for (int k = l; k < K; k += 64) s1 += row[k];
      #pragma unroll
      for (int off = 32; off; off >>= 1) s1 += __shfl_xor(s1, off);
      const float mean = s1 * (1.0f/K);
      float s2 = 0.f;
      for (int k = l; k < K; k += 64) { float d = row[k] - mean; s2 += d*d; }
      #pragma unroll
      for (int off = 32; off; off >>= 1) s2 += __shfl_xor(s2, off);
      const float rstd = 1.0f / sqrtf(s2 * (1.0f/K) + EPSc);
      for (int k = l; k < K; k += 64)
        row[k] = (row[k] - mean) * rstd * lng[k] + lnb[k];
    }
  }
  __syncthreads();
  // ---- Phase G: GEMM. thread = (o_l in 0..15, kc in 0..63); all 16 b in regs ----
  constexpr int KC = K / 64;
  float acc[16];
  if (active) {
    const int o_l = tid & 15, kc = tid >> 4;
    const int o = wg*16 + o_l;
    float wr[KC];
    const float* wp = Wmat + (size_t)(kc*KC)*O + o;
    #pragma unroll
    for (int i = 0; i < KC; i++) wr[i] = wp[(size_t)i * O];
    #pragma unroll
    for (int b = 0; b < 16; b++) acc[b] = 0.f;
    #pragma unroll 2
    for (int b = 0; b < 16; b++) {
      const float4* xr = (const float4*)(X + b*K + kc*KC);
      float t0=0.f, t1=0.f, t2=0.f, t3=0.f;
      #pragma unroll
      for (int q = 0; q < KC/4; q++) {
        float4 xv = xr[q];
        t0 += xv.x * wr[4*q+0];
        t1 += xv.y * wr[4*q+1];
        t2 += xv.z * wr[4*q+2];
        t3 += xv.w * wr[4*q+3];
      }
      acc[b] = (t0+t1) + (t2+t3);
    }
    // in-wave reduce over the 4 kc values living in this wave
    #pragma unroll
    for (int b = 0; b < 16; b++) {
      acc[b] += __shfl_xor(acc[b], 16);
      acc[b] += __shfl_xor(acc[b], 32);
    }
  }
  __syncthreads();                 // X reads done; safe to alias X as pbuf
  float* pbuf = X;                 // [16 wavegrp][16 o_l][16 b]
  if (active && (tid & 63) < 16) {
    const int w = tid >> 6, o_l = tid & 15;
    #pragma unroll
    for (int b = 0; b < 16; b++) pbuf[(w*16 + o_l)*16 + b] = acc[b];
  }
  __syncthreads();
  // ---- Phase R: final reduce + bias + LIF + output writes ----
  if (active && tid < 256) {
    const int o_l = tid & 15, b = tid >> 4;
    const int o = wg*16 + o_l;
    float v = 0.f;
    #pragma unroll
    for (int w = 0; w < 16; w++) v += pbuf[(w*16 + o_l)*16 + b];
    v += bias[o];
    float mt = mem[b*O + o] * DECAYc + v;      // mem: owner-private, cached
    float spk = (mt >= THRc) ? 1.f : 0.f;
    mem[b*O + o] = mt * (1.f - spk);
    if (MODE == 0) {
      st_cg(errw + b*DMn + o, spk);                          // bottom = spike
    } else if (MODE == 1) {
      st_cg(errw + b*DMn + o, ld_cg(errr + b*DMn + o) - spk); // error = bottom - pred
    } else {
      float ns = ld_cg(stw + b*DSn + o) + spk;               // states[j] += upd
      st_cg(stw + b*DSn + o, ns);
      if (hsw) hsw[b*DSn + o] = ns;   // consumed by out_gemm after kernel end
    }
  }
}

__global__ void __launch_bounds__(TPB) snn_scan(SP p, char* __restrict__ ws)
{
  __shared__ float X[16*1024];     // 64 KiB, reused each step (pbuf aliases it)
  const int wg = blockIdx.x, tid = threadIdx.x;
  int*   flags  = (int*)  (ws + OF_FLAGS);
  float* states = (float*)(ws + OF_STATES);
  float* encm   = (float*)(ws + OF_ENCM);
  float* genm   = (float*)(ws + OF_GENM);
  float* infm   = (float*)(ws + OF_INFM);
  float* e0     = (float*)(ws + OF_ERR0);
  float* e1     = (float*)(ws + OF_ERR1);
  float* hs     = (float*)(ws + OF_HS);

  int epoch = 0;
  for (int s = 0; s < Sn; s++) {
    // encoder: emb @ W_enc + b_enc -> LIF -> bottom (err buf 0)
    step_fn<1024,1024,0>(p.W_enc, p.b_enc, nullptr, nullptr, p.emb, p.ids, s,
                         encm, nullptr, e0, nullptr, nullptr, X, wg, tid);
    gbar(flags, wg, tid, ++epoch);
    int pp = 0;
    for (int it = 0; it < 8; it++) {     // it = t*2 + j
      const int j = it & 1;
      // generative: ln(states[j]) @ Wg[j] -> LIF -> pred; error = bottom - pred
      step_fn<512,1024,1>(p.Wg + (size_t)j*512*1024, p.bg + j*1024,
                          p.ln_s_g + j*512, p.ln_s_b + j*512,
                          states + j*16*512, nullptr, 0,
                          genm + j*16*1024,
                          pp ? e1 : e0, pp ? e0 : e1,
                          nullptr, nullptr, X, wg, tid);
      gbar(flags, wg, tid, ++epoch);
      pp ^= 1;
      // inference: ln(error) @ Wi[j] -> LIF -> upd; states[j] += upd
      step_fn<1024,512,2>(p.Wi + (size_t)j*1024*512, p.bi + j*512,
                          p.ln_e_g + j*1024, p.ln_e_b + j*1024,
                          pp ? e1 : e0, nullptr, 0,
                          infm + j*16*512,
                          nullptr, nullptr,
                          states + j*16*512,
                          (it == 7) ? (hs + (size_t)s*16*512) : nullptr,
                          X, wg, tid);
      gbar(flags, wg, tid, ++epoch);
    }
  }
}

// logits = hs @ W_out + b_out, fp32, 128x128 tile, 8x8 microtile
__global__ void __launch_bounds__(256) out_gemm(
    const float* __restrict__ hs, const float* __restrict__ Wo,
    const float* __restrict__ bo, float* __restrict__ out)
{
  __shared__ float As[32][128];    // [k][m]
  __shared__ float Bs[32][128];    // [k][n]
  const int tid = threadIdx.x;
  const int ntile = blockIdx.x * 128;
  const int mtile = blockIdx.y * 128;
  const int tx = tid & 15, ty = tid >> 4;
  float acc[8][8];
  #pragma unroll
  for (int i = 0; i < 8; i++)
    #pragma unroll
    for (int q = 0; q < 8; q++) acc[i][q] = 0.f;

  for (int kb = 0; kb < 16; kb++) {
    #pragma unroll
    for (int r = 0; r < 4; r++) {
      int idx = tid + r*256;             // 1024 float4 slots: 128 m x 8 kq
      int m = idx >> 3, kq = idx & 7;
      float4 a = *(const float4*)(hs + (size_t)(mtile+m)*512 + kb*32 + kq*4);
      As[kq*4+0][m] = a.x; As[kq*4+1][m] = a.y;
      As[kq*4+2][m] = a.z; As[kq*4+3][m] = a.w;
    }
    #pragma unroll
    for (int r = 0; r < 4; r++) {
      int idx = tid + r*256;             // 32 k x 32 nq
      int k = idx >> 5, nq = idx & 31;
      *(float4*)(&Bs[k][nq*4]) =
          *(const float4*)(Wo + (size_t)(kb*32+k)*Vn + ntile + nq*4);
    }
    __syncthreads();
    #pragma unroll
    for (int k = 0; k < 32; k++) {
      float4 a0 = *(float4*)(&As[k][ty*8]);
      float4 a1 = *(float4*)(&As[k][ty*8+4]);
      float4 b0 = *(float4*)(&Bs[k][tx*8]);
      float4 b1 = *(float4*)(&Bs[k][tx*8+4]);
      float av[8] = {a0.x,a0.y,a0.z,a0.w,a1.x,a1.y,a1.z,a1.w};
      float bv[8] = {b0.x,b0.y,b0.z,b0.w,b1.x,b1.y,b1.z,b1.w};
      #pragma unroll
      for (int i = 0; i < 8; i++)
        #pragma unroll
        for (int q = 0; q < 8; q++) acc[i][q] += av[i]*bv[q];
    }
    __syncthreads();
  }
  const float* bop = bo + ntile + tx*8;
  float4 bv0 = *(const float4*)bop;
  float4 bv1 = *(const float4*)(bop + 4);
  #pragma unroll
  for (int i = 0; i < 8; i++) {
    int m = mtile + ty*8 + i;            // m = s*16 + b
    float* op = out + ((size_t)(m & 15)*Sn + (m >> 4))*Vn + ntile + tx*8;
    float4 v0 = make_float4(acc[i][0]+bv0.x, acc[i][1]+bv0.y,
                            acc[i][2]+bv0.z, acc[i][3]+bv0.w);
    float4 v1 = make_float4(acc[i][4]+bv1.x, acc[i][5]+bv1.y,
                            acc[i][6]+bv1.z, acc[i][7]+bv1.w);
    *(float4*)op = v0;
    *(float4*)(op + 4) = v1;
  }
}

extern "C" void kernel_launch(void* const* d_in, const int* in_sizes, int n_in,
                              void* d_out, int out_size, void* d_ws, size_t ws_size,
                              hipStream_t stream) {
  (void)in_sizes; (void)n_in; (void)out_size; (void)ws_size;
  SP p;
  p.ids    = (const int*)  d_in[0];
  p.emb    = (const float*)d_in[1];
  p.W_enc  = (const float*)d_in[2];
  p.b_enc  = (const float*)d_in[3];
  p.ln_s_g = (const float*)d_in[4];
  p.ln_s_b = (const float*)d_in[5];
  p.Wg     = (const float*)d_in[6];
  p.bg     = (const float*)d_in[7];
  p.ln_e_g = (const float*)d_in[8];
  p.ln_e_b = (const float*)d_in[9];
  p.Wi     = (const float*)d_in[10];
  p.bi     = (const float*)d_in[11];
  const float* Wo = (const float*)d_in[12];
  const float* bo = (const float*)d_in[13];

  char* ws = (char*)d_ws;
  hipMemsetAsync(ws, 0, INIT_BYTES, stream);   // flags + carry state = 0
  hipLaunchKernelGGL(snn_scan, dim3(NWG), dim3(TPB), 0, stream, p, ws);
  float* hs = (float*)(ws + OF_HS);
  hipLaunchKernelGGL(out_gemm, dim3(Vn/128, 2048/128), dim3(256), 0, stream,
                     hs, Wo, bo, (float*)d_out);
}

// Round 3
// 24905.338 us; speedup vs baseline: 2.3766x; 1.1795x over previous
//
#include <hip/hip_runtime.h>
#include <math.h>

#define NWG 64
#define TPB 256

typedef float v4f __attribute__((ext_vector_type(4)));

constexpr int Bn = 16, Sn = 128, Vn = 32000, DMn = 1024, DSn = 512;
constexpr float DECAYc = 0.6065306597126334f;  // exp(-1/tau), tau=2
constexpr float THRc = 1.0f, EPSc = 1e-5f;

// ---- workspace byte offsets ----
constexpr size_t OF_FLAGS  = 0;                                   // 64 * 128B
constexpr size_t OF_STATES = 8192;                                // [2][16][512]
constexpr size_t OF_EE     = OF_STATES + (size_t)2*16*512*4;      // [16][1024]
constexpr size_t OF_E0     = OF_EE + (size_t)16*1024*4;
constexpr size_t OF_E1     = OF_E0 + (size_t)16*1024*4;
constexpr size_t OF_HS     = OF_E1 + (size_t)16*1024*4;           // [128][16][512]
constexpr size_t OF_WET    = OF_HS + (size_t)128*16*512*4;        // WencT [1024][1024]
constexpr size_t OF_WGT    = OF_WET + (size_t)1024*1024*4;        // WgT [2][1024][512]
constexpr size_t OF_WIT    = OF_WGT + (size_t)2*1024*512*4;       // WiT [2][512][1024]
constexpr size_t INIT_BYTES = OF_EE;   // zero flags + states

struct SP {
  const int* ids; const float* emb;
  const float* W_enc; const float* b_enc;
  const float* ln_s_g; const float* ln_s_b;
  const float* Wg; const float* bg;
  const float* ln_e_g; const float* ln_e_b;
  const float* Wi; const float* bi;
};

// LLC-coherent (L1+L2 bypass) accesses: no fences needed anywhere.
__device__ __forceinline__ float ld_cg(const float* p) {
  return __hip_atomic_load(p, __ATOMIC_RELAXED, __HIP_MEMORY_SCOPE_AGENT);
}
__device__ __forceinline__ void st_cg(float* p, float v) {
  __hip_atomic_store(p, v, __ATOMIC_RELAXED, __HIP_MEMORY_SCOPE_AGENT);
}

// device-wide barrier, no cache maintenance (all cross-WG data is write-through)
__device__ __forceinline__ void gbar(int* flags, int wg, int tid, int epoch) {
  asm volatile("s_waitcnt vmcnt(0)" ::: "memory");
  __syncthreads();
  if (tid == 0)
    __hip_atomic_store(flags + wg*32, epoch, __ATOMIC_RELAXED, __HIP_MEMORY_SCOPE_AGENT);
  if (tid < NWG) {
    while (__hip_atomic_load(flags + tid*32, __ATOMIC_RELAXED, __HIP_MEMORY_SCOPE_AGENT) < epoch) { }
  }
  asm volatile("" ::: "memory");
  __syncthreads();
}

// 16B-chunk XOR swizzle (involution) for conflict-free strided b128 LDS access
__device__ __forceinline__ int swc(int c) { return c ^ ((c >> 3) & 7); }

// One fused step. Wave w owns outputs o0 + w*OPW + i (i<OPW); lane l owns
// k-chunk [l*Kc, (l+1)*Kc). X [16][K] staged swizzled in LDS.
// MODE: 0 = embedding gather (no LN), 1 = LayerNorm rows from `src` (LLC).
// ROP:  0 enc (errw=spike), 1 gen-first (bottom=ld_cg(errr)), 2 gen-cont
//       (bottom=btreg), 3 inf (streg += spike -> stw, optional hsw).
template<int K, int NO, int MODE, int ROP>
__device__ __forceinline__ void step_fn(
    const float* __restrict__ WT,   // [O][K] transposed weights
    const float* __restrict__ bias,
    const float* __restrict__ lng, const float* __restrict__ lnb,
    const float* __restrict__ src, const int* __restrict__ ids, int s,
    float* __restrict__ mreg, float* __restrict__ btreg, float* __restrict__ streg,
    const float* __restrict__ errr, float* __restrict__ errw,
    float* __restrict__ stw, float* __restrict__ hsw,
    int o0, float* X, int tid)
{
  constexpr int Kc = K / 64, KC4 = Kc / 4, OPW = NO / 4;
  const int w = tid >> 6, l = tid & 63;
  const int g = l >> 4, bsel = l & 15;

  // ---- prefetch bottom values (gen-first) ----
  float eEv[(OPW + 3) / 4];
  if (ROP == 1) {
    #pragma unroll
    for (int i = 0; i < OPW; i++) if ((i & 3) == g) {
      const int o = o0 + w*OPW + i;
      eEv[i >> 2] = ld_cg(errr + bsel*DMn + o);
    }
  }

  // ---- W prefetch: lane l loads k-slice of its wave's o columns (cached/L2) ----
  float wreg[Kc][OPW];
  #pragma unroll
  for (int i = 0; i < OPW; i++) {
    const v4f* wp = (const v4f*)(WT + (size_t)(o0 + w*OPW + i)*K + l*Kc);
    #pragma unroll
    for (int q = 0; q < KC4; q++) {
      v4f v = wp[q];
      #pragma unroll
      for (int e = 0; e < 4; e++) wreg[q*4 + e][i] = v[e];
    }
  }

  // ---- Phase A: stage X into LDS (swizzled), LN if MODE1 ----
  if (MODE == 0) {
    const int b = tid >> 4, sub = tid & 15;
    const int row = ids[b*Sn + s];
    const v4f* er = (const v4f*)(src + (size_t)row*DMn);
    #pragma unroll
    for (int i2 = 0; i2 < 16; i2++) {
      const int c = sub + 16*i2;
      v4f v = er[c];
      *(v4f*)(X + b*K + (swc(c) << 2)) = v;
    }
  } else {
    v4f xr[4][KC4];
    #pragma unroll
    for (int rr = 0; rr < 4; rr++) {
      const float* sp = src + (size_t)(w*4 + rr)*K + l*Kc;
      #pragma unroll
      for (int q = 0; q < KC4; q++)
        asm volatile("global_load_dwordx4 %0, %1, off sc0 sc1"
                     : "=v"(xr[rr][q]) : "v"(sp + 4*q));
    }
    asm volatile("s_waitcnt vmcnt(0)" ::: "memory");
    __builtin_amdgcn_sched_barrier(0);
    #pragma unroll
    for (int rr = 0; rr < 4; rr++) {
      const int b = w*4 + rr;
      float s1 = 0.f;
      #pragma unroll
      for (int q = 0; q < KC4; q++)
        #pragma unroll
        for (int e = 0; e < 4; e++) s1 += xr[rr][q][e];
      #pragma unroll
      for (int off = 32; off; off >>= 1) s1 += __shfl_xor(s1, off);
      const float mean = s1 * (1.0f / K);
      float s2 = 0.f;
      #pragma unroll
      for (int q = 0; q < KC4; q++)
        #pragma unroll
        for (int e = 0; e < 4; e++) { float d = xr[rr][q][e] - mean; s2 += d*d; }
      #pragma unroll
      for (int off = 32; off; off >>= 1) s2 += __shfl_xor(s2, off);
      const float rstd = 1.0f / sqrtf(s2 * (1.0f / K) + EPSc);
      #pragma unroll
      for (int q = 0; q < KC4; q++) {
        v4f ov;
        #pragma unroll
        for (int e = 0; e < 4; e++) {
          const int k = l*Kc + q*4 + e;
          ov[e] = (xr[rr][q][e] - mean) * rstd * lng[k] + lnb[k];
        }
        *(v4f*)(X + b*K + (swc(l*KC4 + q) << 2)) = ov;
      }
    }
  }
  __syncthreads();

  // ---- Phase B: GEMM partials (lane-local K slice) ----
  int xoff[KC4];
  #pragma unroll
  for (int q = 0; q < KC4; q++) xoff[q] = swc(l*KC4 + q) << 2;
  float acc[16][OPW];
  #pragma unroll
  for (int b = 0; b < 16; b++)
    #pragma unroll
    for (int i = 0; i < OPW; i++) acc[b][i] = 0.f;
  #pragma unroll
  for (int b = 0; b < 16; b++) {
    v4f xv[KC4];
    #pragma unroll
    for (int q = 0; q < KC4; q++) xv[q] = *(const v4f*)(X + b*K + xoff[q]);
    #pragma unroll
    for (int i = 0; i < OPW; i++) {
      float a = acc[b][i];
      #pragma unroll
      for (int q = 0; q < KC4; q++)
        #pragma unroll
        for (int e = 0; e < 4; e++) a = fmaf(xv[q][e], wreg[q*4 + e][i], a);
      acc[b][i] = a;
    }
  }

  // ---- cross-lane allreduce over the 64-way K split ----
  #pragma unroll
  for (int b = 0; b < 16; b++)
    #pragma unroll
    for (int i = 0; i < OPW; i++) {
      float v = acc[b][i];
      #pragma unroll
      for (int off = 1; off < 64; off <<= 1) v += __shfl_xor(v, off);
      acc[b][i] = v;
    }

  // ---- Phase R: bias + LIF + outputs. Lane (g,bsel) writes (b=bsel, i≡g mod 4) ----
  #pragma unroll
  for (int i = 0; i < OPW; i++) {
    if ((i & 3) == g) {
      float t = acc[0][i];
      #pragma unroll
      for (int b2 = 1; b2 < 16; b2++) t = (bsel == b2) ? acc[b2][i] : t;
      const int o = o0 + w*OPW + i;
      const float v = t + bias[o];
      const float mt = mreg[i >> 2] * DECAYc + v;
      const float spk = (mt >= THRc) ? 1.f : 0.f;
      mreg[i >> 2] = mt * (1.f - spk);
      if (ROP == 0) {
        st_cg(errw + bsel*DMn + o, spk);
      } else if (ROP == 1) {
        const float ne = eEv[i >> 2] - spk;
        btreg[i >> 2] = ne;
        st_cg(errw + bsel*DMn + o, ne);
      } else if (ROP == 2) {
        const float ne = btreg[i >> 2] - spk;
        btreg[i >> 2] = ne;
        st_cg(errw + bsel*DMn + o, ne);
      } else {
        const float ns = streg[0] + spk;
        streg[0] = ns;
        st_cg(stw + bsel*DSn + o, ns);
        if (hsw) hsw[bsel*DSn + o] = ns;
      }
    }
  }
}

__global__ void __launch_bounds__(TPB, 1) snn_scan(SP p, char* __restrict__ ws)
{
  __shared__ float X[16 * 1024];   // 64 KiB
  const int wg = blockIdx.x, tid = threadIdx.x;
  int*   flags  = (int*)  (ws + OF_FLAGS);
  float* states = (float*)(ws + OF_STATES);
  float* eE     = (float*)(ws + OF_EE);
  float* e0     = (float*)(ws + OF_E0);
  float* e1     = (float*)(ws + OF_E1);
  float* hs     = (float*)(ws + OF_HS);
  const float* WeT = (const float*)(ws + OF_WET);
  const float* WgT = (const float*)(ws + OF_WGT);
  const float* WiT = (const float*)(ws + OF_WIT);
  float* ebuf[2] = { e0, e1 };

  // persistent per-lane state (WG<->output mapping is stable across all phases)
  float encMem = 0.f;
  float genMem[2][2] = {{0.f,0.f},{0.f,0.f}};   // [j][ii]
  float btReg[2] = {0.f, 0.f};                   // gen bottom chain [ii]
  float infMem[2] = {0.f, 0.f};                  // [j]
  float stReg[2]  = {0.f, 0.f};                  // inf-owned states copy [j]

  int epoch = 0;
  for (int s = 0; s < Sn; s++) {
    // P0: encoder (all 64 WGs, 16 o each)
    step_fn<1024,16,0,0>(WeT, p.b_enc, nullptr, nullptr, p.emb, p.ids, s,
                         &encMem, nullptr, nullptr,
                         nullptr, eE, nullptr, nullptr, wg*16, X, tid);
    gbar(flags, wg, tid, ++epoch);

    // P1: gen(0), WGs 0-31, 32 o each; bottom from eE
    if (wg < 32)
      step_fn<512,32,1,1>(WgT, p.bg, p.ln_s_g, p.ln_s_b, states, nullptr, 0,
                          genMem[0], btReg, nullptr,
                          eE, ebuf[0], nullptr, nullptr, wg*32, X, tid);
    gbar(flags, wg, tid, ++epoch);

    // P2..P8: gen(it)=ph-1 on WGs 0-31  ||  inf(it2)=ph-2 on WGs 32-63
    for (int ph = 2; ph <= 8; ph++) {
      if (wg < 32) {
        const int it = ph - 1, j = it & 1;
        step_fn<512,32,1,2>(WgT + (size_t)j*DMn*DSn, p.bg + j*DMn,
                            p.ln_s_g + j*DSn, p.ln_s_b + j*DSn,
                            states + j*Bn*DSn, nullptr, 0,
                            genMem[j], btReg, nullptr,
                            nullptr, ebuf[it & 1], nullptr, nullptr,
                            wg*32, X, tid);
      } else {
        const int it2 = ph - 2, j = it2 & 1;
        step_fn<1024,16,1,3>(WiT + (size_t)j*DSn*DMn, p.bi + j*DSn,
                             p.ln_e_g + j*DMn, p.ln_e_b + j*DMn,
                             ebuf[it2 & 1], nullptr, 0,
                             &infMem[j], nullptr, &stReg[j],
                             nullptr, nullptr, states + j*Bn*DSn, nullptr,
                             (wg - 32)*16, X, tid);
      }
      gbar(flags, wg, tid, ++epoch);
    }

    // P9: inf(7) (j=1), WGs 32-63; also captures hs[s]
    if (wg >= 32)
      step_fn<1024,16,1,3>(WiT + (size_t)1*DSn*DMn, p.bi + DSn,
                           p.ln_e_g + DMn, p.ln_e_b + DMn,
                           ebuf[1], nullptr, 0,
                           &infMem[1], nullptr, &stReg[1],
                           nullptr, nullptr, states + Bn*DSn,
                           hs + (size_t)s*Bn*DSn, (wg - 32)*16, X, tid);
    gbar(flags, wg, tid, ++epoch);
  }
}

// tiled transpose: in [K][O] -> out [O][K]
__global__ void __launch_bounds__(256) transpose_k(
    const float* __restrict__ in, float* __restrict__ out, int K, int O)
{
  __shared__ float t[32][33];
  const int ob = blockIdx.x * 32, kb = blockIdx.y * 32;
  const int x = threadIdx.x, y = threadIdx.y;
  #pragma unroll
  for (int i = 0; i < 32; i += 8) t[y + i][x] = in[(size_t)(kb + y + i)*O + ob + x];
  __syncthreads();
  #pragma unroll
  for (int i = 0; i < 32; i += 8) out[(size_t)(ob + y + i)*K + kb + x] = t[x][y + i];
}

// logits = hs @ W_out + b_out, fp32, 128x128 tile, 8x8 microtile
__global__ void __launch_bounds__(256) out_gemm(
    const float* __restrict__ hs, const float* __restrict__ Wo,
    const float* __restrict__ bo, float* __restrict__ out)
{
  __shared__ float As[32][128];
  __shared__ float Bs[32][128];
  const int tid = threadIdx.x;
  const int ntile = blockIdx.x * 128;
  const int mtile = blockIdx.y * 128;
  const int tx = tid & 15, ty = tid >> 4;
  float acc[8][8];
  #pragma unroll
  for (int i = 0; i < 8; i++)
    #pragma unroll
    for (int q = 0; q < 8; q++) acc[i][q] = 0.f;

  for (int kb = 0; kb < 16; kb++) {
    #pragma unroll
    for (int r = 0; r < 4; r++) {
      int idx = tid + r*256;
      int m = idx >> 3, kq = idx & 7;
      float4 a = *(const float4*)(hs + (size_t)(mtile + m)*512 + kb*32 + kq*4);
      As[kq*4+0][m] = a.x; As[kq*4+1][m] = a.y;
      As[kq*4+2][m] = a.z; As[kq*4+3][m] = a.w;
    }
    #pragma unroll
    for (int r = 0; r < 4; r++) {
      int idx = tid + r*256;
      int k = idx >> 5, nq = idx & 31;
      *(float4*)(&Bs[k][nq*4]) =
          *(const float4*)(Wo + (size_t)(kb*32 + k)*Vn + ntile + nq*4);
    }
    __syncthreads();
    #pragma unroll
    for (int k = 0; k < 32; k++) {
      float4 a0 = *(float4*)(&As[k][ty*8]);
      float4 a1 = *(float4*)(&As[k][ty*8+4]);
      float4 b0 = *(float4*)(&Bs[k][tx*8]);
      float4 b1 = *(float4*)(&Bs[k][tx*8+4]);
      float av[8] = {a0.x,a0.y,a0.z,a0.w,a1.x,a1.y,a1.z,a1.w};
      float bv[8] = {b0.x,b0.y,b0.z,b0.w,b1.x,b1.y,b1.z,b1.w};
      #pragma unroll
      for (int i = 0; i < 8; i++)
        #pragma unroll
        for (int q = 0; q < 8; q++) acc[i][q] += av[i]*bv[q];
    }
    __syncthreads();
  }
  const float* bop = bo + ntile + tx*8;
  float4 bv0 = *(const float4*)bop;
  float4 bv1 = *(const float4*)(bop + 4);
  #pragma unroll
  for (int i = 0; i < 8; i++) {
    int m = mtile + ty*8 + i;            // m = s*16 + b
    float* op = out + ((size_t)(m & 15)*Sn + (m >> 4))*Vn + ntile + tx*8;
    float4 v0 = make_float4(acc[i][0]+bv0.x, acc[i][1]+bv0.y,
                            acc[i][2]+bv0.z, acc[i][3]+bv0.w);
    float4 v1 = make_float4(acc[i][4]+bv1.x, acc[i][5]+bv1.y,
                            acc[i][6]+bv1.z, acc[i][7]+bv1.w);
    *(float4*)op = v0;
    *(float4*)(op + 4) = v1;
  }
}

extern "C" void kernel_launch(void* const* d_in, const int* in_sizes, int n_in,
                              void* d_out, int out_size, void* d_ws, size_t ws_size,
                              hipStream_t stream) {
  (void)in_sizes; (void)n_in; (void)out_size; (void)ws_size;
  SP p;
  p.ids    = (const int*)  d_in[0];
  p.emb    = (const float*)d_in[1];
  p.W_enc  = (const float*)d_in[2];
  p.b_enc  = (const float*)d_in[3];
  p.ln_s_g = (const float*)d_in[4];
  p.ln_s_b = (const float*)d_in[5];
  p.Wg     = (const float*)d_in[6];
  p.bg     = (const float*)d_in[7];
  p.ln_e_g = (const float*)d_in[8];
  p.ln_e_b = (const float*)d_in[9];
  p.Wi     = (const float*)d_in[10];
  p.bi     = (const float*)d_in[11];
  const float* Wo = (const float*)d_in[12];
  const float* bo = (const float*)d_in[13];

  char* ws = (char*)d_ws;
  float* WeT = (float*)(ws + OF_WET);
  float* WgT = (float*)(ws + OF_WGT);
  float* WiT = (float*)(ws + OF_WIT);

  hipMemsetAsync(ws, 0, INIT_BYTES, stream);   // flags + states = 0

  hipLaunchKernelGGL(transpose_k, dim3(32, 32), dim3(32, 8), 0, stream,
                     p.W_enc, WeT, 1024, 1024);
  hipLaunchKernelGGL(transpose_k, dim3(32, 16), dim3(32, 8), 0, stream,
                     p.Wg, WgT, 512, 1024);
  hipLaunchKernelGGL(transpose_k, dim3(32, 16), dim3(32, 8), 0, stream,
                     p.Wg + (size_t)512*1024, WgT + (size_t)1024*512, 512, 1024);
  hipLaunchKernelGGL(transpose_k, dim3(16, 32), dim3(32, 8), 0, stream,
                     p.Wi, WiT, 1024, 512);
  hipLaunchKernelGGL(transpose_k, dim3(16, 32), dim3(32, 8), 0, stream,
                     p.Wi + (size_t)1024*512, WiT + (size_t)512*1024, 1024, 512);

  hipLaunchKernelGGL(snn_scan, dim3(NWG), dim3(TPB), 0, stream, p, ws);

  float* hs = (float*)(ws + OF_HS);
  hipLaunchKernelGGL(out_gemm, dim3(Vn/128, 2048/128), dim3(256), 0, stream,
                     hs, Wo, bo, (float*)d_out);
}

// Round 4
// 14541.368 us; speedup vs baseline: 4.0705x; 1.7127x over previous
//
#include <hip/hip_runtime.h>
#include <math.h>

#define NWG 64
#define TPB 256

typedef float v4f __attribute__((ext_vector_type(4)));

constexpr int Bn = 16, Sn = 128, Vn = 32000, DMn = 1024, DSn = 512;
constexpr float DECAYc = 0.6065306597126334f;  // exp(-1/tau), tau=2
constexpr float THRc = 1.0f, EPSc = 1e-5f;

// ---- workspace byte offsets ----
constexpr size_t OF_FLAGS  = 0;                                   // 64 * 4KB (channel-spread)
constexpr size_t OF_STATES = (size_t)64*4096;                     // [2][16][512]
constexpr size_t OF_EE     = OF_STATES + (size_t)2*16*512*4;      // [16][1024]
constexpr size_t OF_E0     = OF_EE + (size_t)16*1024*4;
constexpr size_t OF_E1     = OF_E0 + (size_t)16*1024*4;
constexpr size_t OF_HS     = OF_E1 + (size_t)16*1024*4;           // [128][16][512]
constexpr size_t OF_WET    = OF_HS + (size_t)128*16*512*4;        // WencT [1024][1024]
constexpr size_t OF_WGT    = OF_WET + (size_t)1024*1024*4;        // WgT [2][1024][512]
constexpr size_t OF_WIT    = OF_WGT + (size_t)2*1024*512*4;       // WiT [2][512][1024]
constexpr size_t INIT_BYTES = OF_EE;   // zero flags + states

struct SP {
  const int* ids; const float* emb;
  const float* W_enc; const float* b_enc;
  const float* ln_s_g; const float* ln_s_b;
  const float* Wg; const float* bg;
  const float* ln_e_g; const float* ln_e_b;
  const float* Wi; const float* bi;
};

// LLC-coherent (L1+L2 bypass) accesses: no fences needed anywhere.
__device__ __forceinline__ float ld_cg(const float* p) {
  return __hip_atomic_load(p, __ATOMIC_RELAXED, __HIP_MEMORY_SCOPE_AGENT);
}
__device__ __forceinline__ void st_cg(float* p, float v) {
  __hip_atomic_store(p, v, __ATOMIC_RELAXED, __HIP_MEMORY_SCOPE_AGENT);
}

// device-wide barrier, no cache maintenance (all cross-WG data is write-through)
__device__ __forceinline__ void gbar(int* flags, int wg, int tid, int epoch) {
  asm volatile("s_waitcnt vmcnt(0)" ::: "memory");
  __syncthreads();
  if (tid == 0)
    __hip_atomic_store(flags + wg*1024, epoch, __ATOMIC_RELAXED, __HIP_MEMORY_SCOPE_AGENT);
  if (tid < NWG) {
    while (__hip_atomic_load(flags + tid*1024, __ATOMIC_RELAXED, __HIP_MEMORY_SCOPE_AGENT) < epoch) { }
  }
  asm volatile("" ::: "memory");
  __syncthreads();
}

// 16B-chunk XOR swizzle (involution) for conflict-free strided b128 LDS access
__device__ __forceinline__ int swc(int c) { return c ^ ((c >> 3) & 7); }

// one butterfly reduce-scatter step: SZ live values -> SZ/2, partner lane ^M.
// lanes with (l&M) keep the upper half of the index space, others the lower.
template<int SZ>
__device__ __forceinline__ void bstep(float* v, bool up, int M) {
  #pragma unroll
  for (int q = 0; q < SZ/2; q++) {
    float lo = v[q], hi = v[q + SZ/2];
    float send = up ? lo : hi;
    float recv = __shfl_xor(send, M);
    v[q] = (up ? hi : lo) + recv;
  }
}

// One fused step. Wave w owns outputs o0 + w*OPW + i (i<OPW); lane l owns
// k-chunk [l*Kc, (l+1)*Kc). X [16][K] staged swizzled in LDS.
// MODE: 0 = embedding gather (no LN), 1 = LayerNorm rows from `src` (LLC).
// ROP:  0 enc (errw=spike), 1 gen-first (bottom=ld_cg(errr)), 2 gen-cont
//       (bottom=btreg), 3 inf (streg += spike -> stw, optional hsw).
// Result mapping after butterfly:
//   OPW==8: lane l -> o = o0+w*8+(l>>3), b = 2*(l&7)+{0,1}  (2 results)
//   OPW==4: lane l -> o = o0+w*4+(l>>4), b = l&15            (1 result)
template<int K, int NO, int MODE, int ROP>
__device__ __forceinline__ void step_fn(
    const float* __restrict__ WT,   // [O][K] transposed weights
    const float* __restrict__ bias,
    const float* __restrict__ lng, const float* __restrict__ lnb,
    const float* __restrict__ src, const int* __restrict__ ids, int s,
    float* __restrict__ mreg, float* __restrict__ btreg, float* __restrict__ streg,
    const float* __restrict__ errr, float* __restrict__ errw,
    float* __restrict__ stw, float* __restrict__ hsw,
    int o0, float* X, int tid)
{
  constexpr int Kc = K / 64, KC4 = Kc / 4, OPW = NO / 4, NV = 16 * OPW;
  const int w = tid >> 6, l = tid & 63;

  // ---- prefetch bottom values (gen-first); overlapped with everything ----
  float eEv[2];
  if (ROP == 1) {
    const int o = o0 + w*8 + (l >> 3);
    eEv[0] = ld_cg(errr + (size_t)(2*(l&7)  )*DMn + o);
    eEv[1] = ld_cg(errr + (size_t)(2*(l&7)+1)*DMn + o);
  }

  // ---- W prefetch: lane l loads k-slice of its wave's o columns (cached/L2) ----
  float wreg[Kc][OPW];
  #pragma unroll
  for (int i = 0; i < OPW; i++) {
    const v4f* wp = (const v4f*)(WT + (size_t)(o0 + w*OPW + i)*K + l*Kc);
    #pragma unroll
    for (int q = 0; q < KC4; q++) {
      v4f v = wp[q];
      #pragma unroll
      for (int e = 0; e < 4; e++) wreg[q*4 + e][i] = v[e];
    }
  }

  // ---- Phase A: stage X into LDS (swizzled), LN if MODE1 ----
  if (MODE == 0) {
    const int b = tid >> 4, sub = tid & 15;
    const int row = ids[b*Sn + s];
    const v4f* er = (const v4f*)(src + (size_t)row*DMn);
    #pragma unroll
    for (int i2 = 0; i2 < 16; i2++) {
      const int c = sub + 16*i2;
      v4f v = er[c];
      *(v4f*)(X + b*K + (swc(c) << 2)) = v;
    }
  } else {
    v4f xr[4][KC4];
    #pragma unroll
    for (int rr = 0; rr < 4; rr++) {
      const float* sp = src + (size_t)(w*4 + rr)*K + l*Kc;
      #pragma unroll
      for (int q = 0; q < KC4; q++)
        asm volatile("global_load_dwordx4 %0, %1, off sc0 sc1"
                     : "=v"(xr[rr][q]) : "v"(sp + 4*q));
    }
    asm volatile("s_waitcnt vmcnt(0)" ::: "memory");
    __builtin_amdgcn_sched_barrier(0);
    #pragma unroll
    for (int rr = 0; rr < 4; rr++) {
      const int b = w*4 + rr;
      float s1 = 0.f;
      #pragma unroll
      for (int q = 0; q < KC4; q++)
        #pragma unroll
        for (int e = 0; e < 4; e++) s1 += xr[rr][q][e];
      #pragma unroll
      for (int off = 32; off; off >>= 1) s1 += __shfl_xor(s1, off);
      const float mean = s1 * (1.0f / K);
      float s2 = 0.f;
      #pragma unroll
      for (int q = 0; q < KC4; q++)
        #pragma unroll
        for (int e = 0; e < 4; e++) { float d = xr[rr][q][e] - mean; s2 += d*d; }
      #pragma unroll
      for (int off = 32; off; off >>= 1) s2 += __shfl_xor(s2, off);
      const float rstd = 1.0f / sqrtf(s2 * (1.0f / K) + EPSc);
      #pragma unroll
      for (int q = 0; q < KC4; q++) {
        v4f ov;
        #pragma unroll
        for (int e = 0; e < 4; e++) {
          const int k = l*Kc + q*4 + e;
          ov[e] = (xr[rr][q][e] - mean) * rstd * lng[k] + lnb[k];
        }
        *(v4f*)(X + b*K + (swc(l*KC4 + q) << 2)) = ov;
      }
    }
  }
  __syncthreads();

  // ---- Phase B: GEMM partials (lane-local K slice). v[i*16+b] ----
  int xoff[KC4];
  #pragma unroll
  for (int q = 0; q < KC4; q++) xoff[q] = swc(l*KC4 + q) << 2;
  float v[NV];
  #pragma unroll
  for (int n = 0; n < NV; n++) v[n] = 0.f;
  #pragma unroll
  for (int b = 0; b < 16; b++) {
    v4f xv[KC4];
    #pragma unroll
    for (int q = 0; q < KC4; q++) xv[q] = *(const v4f*)(X + b*K + xoff[q]);
    #pragma unroll
    for (int i = 0; i < OPW; i++) {
      float a = v[i*16 + b];
      #pragma unroll
      for (int q = 0; q < KC4; q++)
        #pragma unroll
        for (int e = 0; e < 4; e++) a = fmaf(xv[q][e], wreg[q*4 + e][i], a);
      v[i*16 + b] = a;
    }
  }

  // ---- butterfly reduce-scatter over the 64-way K split ----
  if (OPW == 8) {
    bstep<128>(v, (l & 32) != 0, 32);
    bstep<64> (v, (l & 16) != 0, 16);
    bstep<32> (v, (l &  8) != 0,  8);
    bstep<16> (v, (l &  4) != 0,  4);
    bstep<8>  (v, (l &  2) != 0,  2);
    bstep<4>  (v, (l &  1) != 0,  1);
  } else {
    bstep<64> (v, (l & 32) != 0, 32);
    bstep<32> (v, (l & 16) != 0, 16);
    bstep<16> (v, (l &  8) != 0,  8);
    bstep<8>  (v, (l &  4) != 0,  4);
    bstep<4>  (v, (l &  2) != 0,  2);
    bstep<2>  (v, (l &  1) != 0,  1);
  }

  // ---- Phase R: bias + LIF + outputs ----
  if (OPW == 8) {       // gen: 2 results per lane, same o, adjacent b
    const int o = o0 + w*8 + (l >> 3);
    const float bb = bias[o];
    #pragma unroll
    for (int e = 0; e < 2; e++) {
      const int b = 2*(l & 7) + e;
      const float val = v[e] + bb;
      const float mt = mreg[e] * DECAYc + val;
      const float spk = (mt >= THRc) ? 1.f : 0.f;
      mreg[e] = mt * (1.f - spk);
      float ne;
      if (ROP == 1) ne = eEv[e] - spk;
      else          ne = btreg[e] - spk;
      btreg[e] = ne;
      st_cg(errw + (size_t)b*DMn + o, ne);
    }
  } else {              // enc / inf: 1 result per lane
    const int o = o0 + w*4 + (l >> 4);
    const int b = l & 15;
    const float val = v[0] + bias[o];
    const float mt = mreg[0] * DECAYc + val;
    const float spk = (mt >= THRc) ? 1.f : 0.f;
    mreg[0] = mt * (1.f - spk);
    if (ROP == 0) {
      st_cg(errw + (size_t)b*DMn + o, spk);
    } else {
      const float ns = streg[0] + spk;
      streg[0] = ns;
      st_cg(stw + (size_t)b*DSn + o, ns);
      if (hsw) hsw[(size_t)b*DSn + o] = ns;
    }
  }
}

__global__ void __launch_bounds__(TPB, 1) snn_scan(SP p, char* __restrict__ ws)
{
  __shared__ float X[16 * 1024];   // 64 KiB
  const int wg = blockIdx.x, tid = threadIdx.x;
  int*   flags  = (int*)  (ws + OF_FLAGS);
  float* states = (float*)(ws + OF_STATES);
  float* eE     = (float*)(ws + OF_EE);
  float* e0     = (float*)(ws + OF_E0);
  float* e1     = (float*)(ws + OF_E1);
  float* hs     = (float*)(ws + OF_HS);
  const float* WeT = (const float*)(ws + OF_WET);
  const float* WgT = (const float*)(ws + OF_WGT);
  const float* WiT = (const float*)(ws + OF_WIT);
  float* ebuf[2] = { e0, e1 };

  // persistent per-lane state (lane<->(b,o) mapping is stable across phases)
  float encMem = 0.f;
  float genMem[2][2] = {{0.f,0.f},{0.f,0.f}};   // [j][e]  (e = which of 2 b's)
  float btReg[2] = {0.f, 0.f};                   // gen bottom chain [e]
  float infMem[2] = {0.f, 0.f};                  // [j]
  float stReg[2]  = {0.f, 0.f};                  // inf-owned states copy [j]

  int epoch = 0;
  for (int s = 0; s < Sn; s++) {
    // P0: encoder (all 64 WGs, 16 o each)
    step_fn<1024,16,0,0>(WeT, p.b_enc, nullptr, nullptr, p.emb, p.ids, s,
                         &encMem, nullptr, nullptr,
                         nullptr, eE, nullptr, nullptr, wg*16, X, tid);
    gbar(flags, wg, tid, ++epoch);

    // P1: gen(0), WGs 0-31, 32 o each; bottom from eE
    if (wg < 32)
      step_fn<512,32,1,1>(WgT, p.bg, p.ln_s_g, p.ln_s_b, states, nullptr, 0,
                          genMem[0], btReg, nullptr,
                          eE, ebuf[0], nullptr, nullptr, wg*32, X, tid);
    gbar(flags, wg, tid, ++epoch);

    // P2..P8: gen(it)=ph-1 on WGs 0-31  ||  inf(it2)=ph-2 on WGs 32-63
    for (int ph = 2; ph <= 8; ph++) {
      if (wg < 32) {
        const int it = ph - 1, j = it & 1;
        step_fn<512,32,1,2>(WgT + (size_t)j*DMn*DSn, p.bg + j*DMn,
                            p.ln_s_g + j*DSn, p.ln_s_b + j*DSn,
                            states + j*Bn*DSn, nullptr, 0,
                            genMem[j], btReg, nullptr,
                            nullptr, ebuf[it & 1], nullptr, nullptr,
                            wg*32, X, tid);
      } else {
        const int it2 = ph - 2, j = it2 & 1;
        step_fn<1024,16,1,3>(WiT + (size_t)j*DSn*DMn, p.bi + j*DSn,
                             p.ln_e_g + j*DMn, p.ln_e_b + j*DMn,
                             ebuf[it2 & 1], nullptr, 0,
                             &infMem[j], nullptr, &stReg[j],
                             nullptr, nullptr, states + j*Bn*DSn, nullptr,
                             (wg - 32)*16, X, tid);
      }
      gbar(flags, wg, tid, ++epoch);
    }

    // P9: inf(7) (j=1), WGs 32-63; also captures hs[s]
    if (wg >= 32)
      step_fn<1024,16,1,3>(WiT + (size_t)1*DSn*DMn, p.bi + DSn,
                           p.ln_e_g + DMn, p.ln_e_b + DMn,
                           ebuf[1], nullptr, 0,
                           &infMem[1], nullptr, &stReg[1],
                           nullptr, nullptr, states + Bn*DSn,
                           hs + (size_t)s*Bn*DSn, (wg - 32)*16, X, tid);
    gbar(flags, wg, tid, ++epoch);
  }
}

// tiled transpose: in [K][O] -> out [O][K]
__global__ void __launch_bounds__(256) transpose_k(
    const float* __restrict__ in, float* __restrict__ out, int K, int O)
{
  __shared__ float t[32][33];
  const int ob = blockIdx.x * 32, kb = blockIdx.y * 32;
  const int x = threadIdx.x, y = threadIdx.y;
  #pragma unroll
  for (int i = 0; i < 32; i += 8) t[y + i][x] = in[(size_t)(kb + y + i)*O + ob + x];
  __syncthreads();
  #pragma unroll
  for (int i = 0; i < 32; i += 8) out[(size_t)(ob + y + i)*K + kb + x] = t[x][y + i];
}

// logits = hs @ W_out + b_out, fp32, 128x128 tile, 8x8 microtile
__global__ void __launch_bounds__(256) out_gemm(
    const float* __restrict__ hs, const float* __restrict__ Wo,
    const float* __restrict__ bo, float* __restrict__ out)
{
  __shared__ float As[32][128];
  __shared__ float Bs[32][128];
  const int tid = threadIdx.x;
  const int ntile = blockIdx.x * 128;
  const int mtile = blockIdx.y * 128;
  const int tx = tid & 15, ty = tid >> 4;
  float acc[8][8];
  #pragma unroll
  for (int i = 0; i < 8; i++)
    #pragma unroll
    for (int q = 0; q < 8; q++) acc[i][q] = 0.f;

  for (int kb = 0; kb < 16; kb++) {
    #pragma unroll
    for (int r = 0; r < 4; r++) {
      int idx = tid + r*256;
      int m = idx >> 3, kq = idx & 7;
      float4 a = *(const float4*)(hs + (size_t)(mtile + m)*512 + kb*32 + kq*4);
      As[kq*4+0][m] = a.x; As[kq*4+1][m] = a.y;
      As[kq*4+2][m] = a.z; As[kq*4+3][m] = a.w;
    }
    #pragma unroll
    for (int r = 0; r < 4; r++) {
      int idx = tid + r*256;
      int k = idx >> 5, nq = idx & 31;
      *(float4*)(&Bs[k][nq*4]) =
          *(const float4*)(Wo + (size_t)(kb*32 + k)*Vn + ntile + nq*4);
    }
    __syncthreads();
    #pragma unroll
    for (int k = 0; k < 32; k++) {
      float4 a0 = *(float4*)(&As[k][ty*8]);
      float4 a1 = *(float4*)(&As[k][ty*8+4]);
      float4 b0 = *(float4*)(&Bs[k][tx*8]);
      float4 b1 = *(float4*)(&Bs[k][tx*8+4]);
      float av[8] = {a0.x,a0.y,a0.z,a0.w,a1.x,a1.y,a1.z,a1.w};
      float bv[8] = {b0.x,b0.y,b0.z,b0.w,b1.x,b1.y,b1.z,b1.w};
      #pragma unroll
      for (int i = 0; i < 8; i++)
        #pragma unroll
        for (int q = 0; q < 8; q++) acc[i][q] += av[i]*bv[q];
    }
    __syncthreads();
  }
  const float* bop = bo + ntile + tx*8;
  float4 bv0 = *(const float4*)bop;
  float4 bv1 = *(const float4*)(bop + 4);
  #pragma unroll
  for (int i = 0; i < 8; i++) {
    int m = mtile + ty*8 + i;            // m = s*16 + b
    float* op = out + ((size_t)(m & 15)*Sn + (m >> 4))*Vn + ntile + tx*8;
    float4 v0 = make_float4(acc[i][0]+bv0.x, acc[i][1]+bv0.y,
                            acc[i][2]+bv0.z, acc[i][3]+bv0.w);
    float4 v1 = make_float4(acc[i][4]+bv1.x, acc[i][5]+bv1.y,
                            acc[i][6]+bv1.z, acc[i][7]+bv1.w);
    *(float4*)op = v0;
    *(float4*)(op + 4) = v1;
  }
}

extern "C" void kernel_launch(void* const* d_in, const int* in_sizes, int n_in,
                              void* d_out, int out_size, void* d_ws, size_t ws_size,
                              hipStream_t stream) {
  (void)in_sizes; (void)n_in; (void)out_size; (void)ws_size;
  SP p;
  p.ids    = (const int*)  d_in[0];
  p.emb    = (const float*)d_in[1];
  p.W_enc  = (const float*)d_in[2];
  p.b_enc  = (const float*)d_in[3];
  p.ln_s_g = (const float*)d_in[4];
  p.ln_s_b = (const float*)d_in[5];
  p.Wg     = (const float*)d_in[6];
  p.bg     = (const float*)d_in[7];
  p.ln_e_g = (const float*)d_in[8];
  p.ln_e_b = (const float*)d_in[9];
  p.Wi     = (const float*)d_in[10];
  p.bi     = (const float*)d_in[11];
  const float* Wo = (const float*)d_in[12];
  const float* bo = (const float*)d_in[13];

  char* ws = (char*)d_ws;
  float* WeT = (float*)(ws + OF_WET);
  float* WgT = (float*)(ws + OF_WGT);
  float* WiT = (float*)(ws + OF_WIT);

  hipMemsetAsync(ws, 0, INIT_BYTES, stream);   // flags + states = 0

  hipLaunchKernelGGL(transpose_k, dim3(32, 32), dim3(32, 8), 0, stream,
                     p.W_enc, WeT, 1024, 1024);
  hipLaunchKernelGGL(transpose_k, dim3(32, 16), dim3(32, 8), 0, stream,
                     p.Wg, WgT, 512, 1024);
  hipLaunchKernelGGL(transpose_k, dim3(32, 16), dim3(32, 8), 0, stream,
                     p.Wg + (size_t)512*1024, WgT + (size_t)1024*512, 512, 1024);
  hipLaunchKernelGGL(transpose_k, dim3(16, 32), dim3(32, 8), 0, stream,
                     p.Wi, WiT, 1024, 512);
  hipLaunchKernelGGL(transpose_k, dim3(16, 32), dim3(32, 8), 0, stream,
                     p.Wi + (size_t)1024*512, WiT + (size_t)512*1024, 1024, 512);

  hipLaunchKernelGGL(snn_scan, dim3(NWG), dim3(TPB), 0, stream, p, ws);

  float* hs = (float*)(ws + OF_HS);
  hipLaunchKernelGGL(out_gemm, dim3(Vn/128, 2048/128), dim3(256), 0, stream,
                     hs, Wo, bo, (float*)d_out);
}

// Round 5
// 6209.955 us; speedup vs baseline: 9.5315x; 2.3416x over previous
//
#include <hip/hip_runtime.h>
#include <math.h>

#define NWG 256
#define TPB 256
#define NGRP 4

typedef float v4f __attribute__((ext_vector_type(4)));

constexpr int Bn = 16, Sn = 128, Vn = 32000, DMn = 1024, DSn = 512;
constexpr float DECAYc = 0.6065306597126334f;  // exp(-1/tau), tau=2
constexpr float THRc = 1.0f, EPSc = 1e-5f;

// ---- workspace byte offsets ----
constexpr size_t OF_FLAGS  = 0;                                   // 256 WGs * 4KB
constexpr size_t OF_STATES = (size_t)256*4096;                    // [2][16][512]
constexpr size_t OF_E0     = OF_STATES + (size_t)2*16*512*4;      // [16][1024]
constexpr size_t OF_E1     = OF_E0 + (size_t)16*1024*4;
constexpr size_t OF_ENCX   = OF_E1 + (size_t)16*1024*4;           // [128][16][1024] gemm->spikes (in-place)
constexpr size_t OF_HS     = OF_ENCX + (size_t)128*16*1024*4;     // [128][16][512]
constexpr size_t OF_WGT    = OF_HS + (size_t)128*16*512*4;        // WgT [2][1024][512]
constexpr size_t OF_WIT    = OF_WGT + (size_t)2*1024*512*4;       // WiT [2][512][1024]
constexpr size_t INIT_BYTES = OF_E0;   // zero flags + states

struct SP {
  const int* ids; const float* emb;
  const float* W_enc; const float* b_enc;
  const float* ln_s_g; const float* ln_s_b;
  const float* Wg; const float* bg;
  const float* ln_e_g; const float* ln_e_b;
  const float* Wi; const float* bi;
};

// LLC-coherent (L1+L2 bypass) accesses: no fences needed anywhere.
__device__ __forceinline__ float ld_cg(const float* p) {
  return __hip_atomic_load(p, __ATOMIC_RELAXED, __HIP_MEMORY_SCOPE_AGENT);
}
__device__ __forceinline__ void st_cg(float* p, float v) {
  __hip_atomic_store(p, v, __ATOMIC_RELAXED, __HIP_MEMORY_SCOPE_AGENT);
}

// group-scope barrier (64 WGs of this group), no cache maintenance
__device__ __forceinline__ void gbar(int* flags, int wgg, int grp, int tid, int epoch) {
  asm volatile("s_waitcnt vmcnt(0)" ::: "memory");
  __syncthreads();
  if (tid == 0)
    __hip_atomic_store(flags + wgg*1024, epoch, __ATOMIC_RELAXED, __HIP_MEMORY_SCOPE_AGENT);
  if (tid < 64) {
    while (__hip_atomic_load(flags + (grp*64 + tid)*1024, __ATOMIC_RELAXED, __HIP_MEMORY_SCOPE_AGENT) < epoch) { }
  }
  asm volatile("" ::: "memory");
  __syncthreads();
}

// 16B-chunk XOR swizzle (involution) for conflict-reduced strided b128 LDS access
__device__ __forceinline__ int swc(int c) { return c ^ ((c >> 3) & 7); }

// one butterfly reduce-scatter step: SZ live values -> SZ/2, partner lane ^M.
template<int SZ>
__device__ __forceinline__ void bstep(float* v, bool up, int M) {
  #pragma unroll
  for (int q = 0; q < SZ/2; q++) {
    float lo = v[q], hi = v[q + SZ/2];
    float send = up ? lo : hi;
    float recv = __shfl_xor(send, M);
    v[q] = (up ? hi : lo) + recv;
  }
}

// One fused step for a group owning batch rows grp*4..grp*4+3.
// Wave w owns outputs o0+w*OPW+i; lane l owns k-chunk [l*Kc,(l+1)*Kc).
// ROP: 1 gen-first (bottom from errr=encX spikes), 2 gen-cont (bottom=btreg),
//      3 inf (streg += spike -> stw, optional hsw).
// Result per lane after butterfly:
//   OPW==8: o_i=(l>>3)&7, b_loc=(l>>1)&3   (lanes l,l^1 duplicate)
//   OPW==4: o_i=(l>>4)&3, b_loc=(l>>2)&3   (lanes l&~3.. duplicate 4-way)
template<int K, int NO, int ROP>
__device__ __forceinline__ void step_fn(
    const float* __restrict__ WT,   // [O][K] transposed weights
    const float* __restrict__ bias,
    const float* __restrict__ lng, const float* __restrict__ lnb,
    const float* __restrict__ src,  // [16][K] rows (LLC-coherent)
    float* __restrict__ mreg, float* __restrict__ btreg, float* __restrict__ streg,
    const float* __restrict__ errr, float* __restrict__ errw,
    float* __restrict__ stw, float* __restrict__ hsw,
    int o0, int grp, float* X, int tid)
{
  constexpr int Kc = K / 64, KC4 = Kc / 4, OPW = NO / 4, NV = 4 * OPW;
  const int w = tid >> 6, l = tid & 63;
  const int o_i   = (OPW == 8) ? ((l >> 3) & 7) : ((l >> 4) & 3);
  const int b_loc = (OPW == 8) ? ((l >> 1) & 3) : ((l >> 2) & 3);
  const int o  = o0 + w*OPW + o_i;
  const int bg = grp*4 + b_loc;

  // ---- prefetch bottom value (gen-first) ----
  float eEv = 0.f;
  if (ROP == 1) eEv = ld_cg(errr + (size_t)bg*DMn + o);

  // ---- W prefetch: lane l loads its k-slice of the wave's o columns (L2) ----
  float wreg[Kc][OPW];
  #pragma unroll
  for (int i = 0; i < OPW; i++) {
    const v4f* wp = (const v4f*)(WT + (size_t)(o0 + w*OPW + i)*K + l*Kc);
    #pragma unroll
    for (int q = 0; q < KC4; q++) {
      v4f v = wp[q];
      #pragma unroll
      for (int e = 0; e < 4; e++) wreg[q*4 + e][i] = v[e];
    }
  }

  // ---- stage + LayerNorm: wave w handles group row w ----
  {
    v4f xr[KC4];
    const float* sp = src + (size_t)(grp*4 + w)*K + l*Kc;
    #pragma unroll
    for (int q = 0; q < KC4; q++)
      asm volatile("global_load_dwordx4 %0, %1, off sc0 sc1"
                   : "=v"(xr[q]) : "v"(sp + 4*q));
    asm volatile("s_waitcnt vmcnt(0)" ::: "memory");
    __builtin_amdgcn_sched_barrier(0);
    float s1 = 0.f;
    #pragma unroll
    for (int q = 0; q < KC4; q++)
      #pragma unroll
      for (int e = 0; e < 4; e++) s1 += xr[q][e];
    #pragma unroll
    for (int off = 32; off; off >>= 1) s1 += __shfl_xor(s1, off);
    const float mean = s1 * (1.0f / K);
    float s2 = 0.f;
    #pragma unroll
    for (int q = 0; q < KC4; q++)
      #pragma unroll
      for (int e = 0; e < 4; e++) { float d = xr[q][e] - mean; s2 += d*d; }
    #pragma unroll
    for (int off = 32; off; off >>= 1) s2 += __shfl_xor(s2, off);
    const float rstd = 1.0f / sqrtf(s2 * (1.0f / K) + EPSc);
    #pragma unroll
    for (int q = 0; q < KC4; q++) {
      v4f ov;
      #pragma unroll
      for (int e = 0; e < 4; e++) {
        const int k = l*Kc + q*4 + e;
        ov[e] = (xr[q][e] - mean) * rstd * lng[k] + lnb[k];
      }
      *(v4f*)(X + w*K + (swc(l*KC4 + q) << 2)) = ov;
    }
  }
  __syncthreads();

  // ---- GEMM partials over lane-local K slice; v[i*4+b] ----
  int xoff[KC4];
  #pragma unroll
  for (int q = 0; q < KC4; q++) xoff[q] = swc(l*KC4 + q) << 2;
  float v[NV];
  #pragma unroll
  for (int n = 0; n < NV; n++) v[n] = 0.f;
  #pragma unroll
  for (int b = 0; b < 4; b++) {
    v4f xv[KC4];
    #pragma unroll
    for (int q = 0; q < KC4; q++) xv[q] = *(const v4f*)(X + b*K + xoff[q]);
    #pragma unroll
    for (int i = 0; i < OPW; i++) {
      float a = v[i*4 + b];
      #pragma unroll
      for (int q = 0; q < KC4; q++)
        #pragma unroll
        for (int e = 0; e < 4; e++) a = fmaf(xv[q][e], wreg[q*4 + e][i], a);
      v[i*4 + b] = a;
    }
  }

  // ---- butterfly reduce-scatter over the 64-way K split ----
  if (OPW == 8) {
    bstep<32>(v, (l & 32) != 0, 32);
    bstep<16>(v, (l & 16) != 0, 16);
    bstep<8> (v, (l &  8) != 0,  8);
    bstep<4> (v, (l &  4) != 0,  4);
    bstep<2> (v, (l &  2) != 0,  2);
    v[0] += __shfl_xor(v[0], 1);           // lanes l,l^1 duplicate
  } else {
    bstep<16>(v, (l & 32) != 0, 32);
    bstep<8> (v, (l & 16) != 0, 16);
    bstep<4> (v, (l &  8) != 0,  8);
    bstep<2> (v, (l &  4) != 0,  4);
    v[0] += __shfl_xor(v[0], 2);           // 4-way duplicate
    v[0] += __shfl_xor(v[0], 1);
  }

  // ---- bias + LIF + outputs ----
  const float val = v[0] + bias[o];
  const float mt = mreg[0] * DECAYc + val;
  const float spk = (mt >= THRc) ? 1.f : 0.f;
  mreg[0] = mt * (1.f - spk);
  if (ROP == 1 || ROP == 2) {
    const float ne = ((ROP == 1) ? eEv : btreg[0]) - spk;
    btreg[0] = ne;
    if ((l & 1) == 0) st_cg(errw + (size_t)bg*DMn + o, ne);
  } else {
    const float ns = streg[0] + spk;
    streg[0] = ns;
    if ((l & 3) == 0) {
      st_cg(stw + (size_t)bg*DSn + o, ns);
      if (hsw) hsw[(size_t)bg*DSn + o] = ns;
    }
  }
}

__global__ void __launch_bounds__(TPB, 1) snn_scan(SP p, char* __restrict__ ws)
{
  __shared__ float X[21504];       // 84 KiB -> forces 1 WG/CU (co-residency)
  const int wgg = blockIdx.x, tid = threadIdx.x;
  const int grp = wgg >> 6, wgl = wgg & 63;
  int*   flags  = (int*)  (ws + OF_FLAGS);
  float* states = (float*)(ws + OF_STATES);
  float* e0     = (float*)(ws + OF_E0);
  float* e1     = (float*)(ws + OF_E1);
  const float* encX = (const float*)(ws + OF_ENCX);   // spikes after lif_scan
  float* hs     = (float*)(ws + OF_HS);
  const float* WgT = (const float*)(ws + OF_WGT);
  const float* WiT = (const float*)(ws + OF_WIT);
  float* ebuf[2] = { e0, e1 };

  float genMem[2] = {0.f, 0.f};
  float btReg = 0.f;
  float infMem[2] = {0.f, 0.f};
  float stReg[2]  = {0.f, 0.f};

  int epoch = 0;
  for (int s = 0; s < Sn; s++) {
    // P1: gen(0) on wgl<32; bottom from precomputed encoder spikes
    if (wgl < 32)
      step_fn<512,32,1>(WgT, p.bg, p.ln_s_g, p.ln_s_b, states,
                        &genMem[0], &btReg, nullptr,
                        encX + (size_t)s*Bn*DMn, ebuf[0],
                        nullptr, nullptr, wgl*32, grp, X, tid);
    gbar(flags, wgg, grp, tid, ++epoch);

    // P2..P8: gen(it=ph-1) on wgl<32 || inf(it2=ph-2) on wgl>=32
    for (int ph = 2; ph <= 8; ph++) {
      if (wgl < 32) {
        const int it = ph - 1, j = it & 1;
        step_fn<512,32,2>(WgT + (size_t)j*DMn*DSn, p.bg + j*DMn,
                          p.ln_s_g + j*DSn, p.ln_s_b + j*DSn,
                          states + (size_t)j*Bn*DSn,
                          &genMem[j], &btReg, nullptr,
                          nullptr, ebuf[it & 1],
                          nullptr, nullptr, wgl*32, grp, X, tid);
      } else {
        const int it2 = ph - 2, j = it2 & 1;
        step_fn<1024,16,3>(WiT + (size_t)j*DSn*DMn, p.bi + j*DSn,
                           p.ln_e_g + j*DMn, p.ln_e_b + j*DMn,
                           ebuf[it2 & 1],
                           &infMem[j], nullptr, &stReg[j],
                           nullptr, nullptr,
                           states + (size_t)j*Bn*DSn, nullptr,
                           (wgl - 32)*16, grp, X, tid);
      }
      gbar(flags, wgg, grp, tid, ++epoch);
    }

    // P9: inf(7) (j=1) on wgl>=32; captures hs[s]
    if (wgl >= 32)
      step_fn<1024,16,3>(WiT + (size_t)DSn*DMn, p.bi + DSn,
                         p.ln_e_g + DMn, p.ln_e_b + DMn,
                         ebuf[1],
                         &infMem[1], nullptr, &stReg[1],
                         nullptr, nullptr,
                         states + (size_t)Bn*DSn,
                         hs + (size_t)s*Bn*DSn, (wgl - 32)*16, grp, X, tid);
    gbar(flags, wgg, grp, tid, ++epoch);
  }
}

// tiled transpose: in [K][O] -> out [O][K]
__global__ void __launch_bounds__(256) transpose_k(
    const float* __restrict__ in, float* __restrict__ out, int K, int O)
{
  __shared__ float t[32][33];
  const int ob = blockIdx.x * 32, kb = blockIdx.y * 32;
  const int x = threadIdx.x, y = threadIdx.y;
  #pragma unroll
  for (int i = 0; i < 32; i += 8) t[y + i][x] = in[(size_t)(kb + y + i)*O + ob + x];
  __syncthreads();
  #pragma unroll
  for (int i = 0; i < 32; i += 8) out[(size_t)(ob + y + i)*K + kb + x] = t[x][y + i];
}

// encX = gather(emb, ids) @ W_enc + b_enc   (M=2048, K=1024, N=1024)
__global__ void __launch_bounds__(256) enc_gemm(
    const int* __restrict__ ids, const float* __restrict__ emb,
    const float* __restrict__ We, const float* __restrict__ be,
    float* __restrict__ encX)
{
  __shared__ float As[32][128];
  __shared__ float Bs[32][128];
  __shared__ int rowid[128];
  const int tid = threadIdx.x;
  const int ntile = blockIdx.x * 128;
  const int mtile = blockIdx.y * 128;
  if (tid < 128) {
    int m = mtile + tid;                  // m = s*16 + b
    rowid[tid] = ids[(m & 15)*Sn + (m >> 4)];
  }
  __syncthreads();
  const int tx = tid & 15, ty = tid >> 4;
  float acc[8][8];
  #pragma unroll
  for (int i = 0; i < 8; i++)
    #pragma unroll
    for (int q = 0; q < 8; q++) acc[i][q] = 0.f;

  for (int kb = 0; kb < 32; kb++) {
    #pragma unroll
    for (int r = 0; r < 4; r++) {
      int idx = tid + r*256;
      int m = idx >> 3, kq = idx & 7;
      float4 a = *(const float4*)(emb + (size_t)rowid[m]*DMn + kb*32 + kq*4);
      As[kq*4+0][m] = a.x; As[kq*4+1][m] = a.y;
      As[kq*4+2][m] = a.z; As[kq*4+3][m] = a.w;
    }
    #pragma unroll
    for (int r = 0; r < 4; r++) {
      int idx = tid + r*256;
      int k = idx >> 5, nq = idx & 31;
      *(float4*)(&Bs[k][nq*4]) =
          *(const float4*)(We + (size_t)(kb*32 + k)*DMn + ntile + nq*4);
    }
    __syncthreads();
    #pragma unroll
    for (int k = 0; k < 32; k++) {
      float4 a0 = *(float4*)(&As[k][ty*8]);
      float4 a1 = *(float4*)(&As[k][ty*8+4]);
      float4 b0 = *(float4*)(&Bs[k][tx*8]);
      float4 b1 = *(float4*)(&Bs[k][tx*8+4]);
      float av[8] = {a0.x,a0.y,a0.z,a0.w,a1.x,a1.y,a1.z,a1.w};
      float bv[8] = {b0.x,b0.y,b0.z,b0.w,b1.x,b1.y,b1.z,b1.w};
      #pragma unroll
      for (int i = 0; i < 8; i++)
        #pragma unroll
        for (int q = 0; q < 8; q++) acc[i][q] += av[i]*bv[q];
    }
    __syncthreads();
  }
  const float* bop = be + ntile + tx*8;
  float4 bv0 = *(const float4*)bop;
  float4 bv1 = *(const float4*)(bop + 4);
  #pragma unroll
  for (int i = 0; i < 8; i++) {
    int m = mtile + ty*8 + i;
    float* op = encX + (size_t)m*DMn + ntile + tx*8;
    float4 v0 = make_float4(acc[i][0]+bv0.x, acc[i][1]+bv0.y,
                            acc[i][2]+bv0.z, acc[i][3]+bv0.w);
    float4 v1 = make_float4(acc[i][4]+bv1.x, acc[i][5]+bv1.y,
                            acc[i][6]+bv1.z, acc[i][7]+bv1.w);
    *(float4*)op = v0;
    *(float4*)(op + 4) = v1;
  }
}

// sequential encoder LIF over s, elementwise per (b,o); in-place encX -> spikes
__global__ void __launch_bounds__(256) lif_scan(float* __restrict__ encX)
{
  const int t = blockIdx.x * 256 + threadIdx.x;   // 16384 threads
  const int b = t >> 10, o = t & 1023;
  float mem = 0.f;
  for (int s = 0; s < Sn; s++) {
    float* p = encX + ((size_t)s*Bn + b)*DMn + o;
    const float x = *p;
    const float mt = mem * DECAYc + x;
    const float spk = (mt >= THRc) ? 1.f : 0.f;
    mem = mt * (1.f - spk);
    *p = spk;
  }
}

// logits = hs @ W_out + b_out, fp32, 128x128 tile, 8x8 microtile
__global__ void __launch_bounds__(256) out_gemm(
    const float* __restrict__ hs, const float* __restrict__ Wo,
    const float* __restrict__ bo, float* __restrict__ out)
{
  __shared__ float As[32][128];
  __shared__ float Bs[32][128];
  const int tid = threadIdx.x;
  const int ntile = blockIdx.x * 128;
  const int mtile = blockIdx.y * 128;
  const int tx = tid & 15, ty = tid >> 4;
  float acc[8][8];
  #pragma unroll
  for (int i = 0; i < 8; i++)
    #pragma unroll
    for (int q = 0; q < 8; q++) acc[i][q] = 0.f;

  for (int kb = 0; kb < 16; kb++) {
    #pragma unroll
    for (int r = 0; r < 4; r++) {
      int idx = tid + r*256;
      int m = idx >> 3, kq = idx & 7;
      float4 a = *(const float4*)(hs + (size_t)(mtile + m)*512 + kb*32 + kq*4);
      As[kq*4+0][m] = a.x; As[kq*4+1][m] = a.y;
      As[kq*4+2][m] = a.z; As[kq*4+3][m] = a.w;
    }
    #pragma unroll
    for (int r = 0; r < 4; r++) {
      int idx = tid + r*256;
      int k = idx >> 5, nq = idx & 31;
      *(float4*)(&Bs[k][nq*4]) =
          *(const float4*)(Wo + (size_t)(kb*32 + k)*Vn + ntile + nq*4);
    }
    __syncthreads();
    #pragma unroll
    for (int k = 0; k < 32; k++) {
      float4 a0 = *(float4*)(&As[k][ty*8]);
      float4 a1 = *(float4*)(&As[k][ty*8+4]);
      float4 b0 = *(float4*)(&Bs[k][tx*8]);
      float4 b1 = *(float4*)(&Bs[k][tx*8+4]);
      float av[8] = {a0.x,a0.y,a0.z,a0.w,a1.x,a1.y,a1.z,a1.w};
      float bv[8] = {b0.x,b0.y,b0.z,b0.w,b1.x,b1.y,b1.z,b1.w};
      #pragma unroll
      for (int i = 0; i < 8; i++)
        #pragma unroll
        for (int q = 0; q < 8; q++) acc[i][q] += av[i]*bv[q];
    }
    __syncthreads();
  }
  const float* bop = bo + ntile + tx*8;
  float4 bv0 = *(const float4*)bop;
  float4 bv1 = *(const float4*)(bop + 4);
  #pragma unroll
  for (int i = 0; i < 8; i++) {
    int m = mtile + ty*8 + i;            // m = s*16 + b
    float* op = out + ((size_t)(m & 15)*Sn + (m >> 4))*Vn + ntile + tx*8;
    float4 v0 = make_float4(acc[i][0]+bv0.x, acc[i][1]+bv0.y,
                            acc[i][2]+bv0.z, acc[i][3]+bv0.w);
    float4 v1 = make_float4(acc[i][4]+bv1.x, acc[i][5]+bv1.y,
                            acc[i][6]+bv1.z, acc[i][7]+bv1.w);
    *(float4*)op = v0;
    *(float4*)(op + 4) = v1;
  }
}

extern "C" void kernel_launch(void* const* d_in, const int* in_sizes, int n_in,
                              void* d_out, int out_size, void* d_ws, size_t ws_size,
                              hipStream_t stream) {
  (void)in_sizes; (void)n_in; (void)out_size; (void)ws_size;
  SP p;
  p.ids    = (const int*)  d_in[0];
  p.emb    = (const float*)d_in[1];
  p.W_enc  = (const float*)d_in[2];
  p.b_enc  = (const float*)d_in[3];
  p.ln_s_g = (const float*)d_in[4];
  p.ln_s_b = (const float*)d_in[5];
  p.Wg     = (const float*)d_in[6];
  p.bg     = (const float*)d_in[7];
  p.ln_e_g = (const float*)d_in[8];
  p.ln_e_b = (const float*)d_in[9];
  p.Wi     = (const float*)d_in[10];
  p.bi     = (const float*)d_in[11];
  const float* Wo = (const float*)d_in[12];
  const float* bo = (const float*)d_in[13];

  char* ws = (char*)d_ws;
  float* WgT  = (float*)(ws + OF_WGT);
  float* WiT  = (float*)(ws + OF_WIT);
  float* encX = (float*)(ws + OF_ENCX);
  float* hs   = (float*)(ws + OF_HS);

  hipMemsetAsync(ws, 0, INIT_BYTES, stream);   // flags + states = 0

  hipLaunchKernelGGL(transpose_k, dim3(32, 16), dim3(32, 8), 0, stream,
                     p.Wg, WgT, 512, 1024);
  hipLaunchKernelGGL(transpose_k, dim3(32, 16), dim3(32, 8), 0, stream,
                     p.Wg + (size_t)512*1024, WgT + (size_t)1024*512, 512, 1024);
  hipLaunchKernelGGL(transpose_k, dim3(16, 32), dim3(32, 8), 0, stream,
                     p.Wi, WiT, 1024, 512);
  hipLaunchKernelGGL(transpose_k, dim3(16, 32), dim3(32, 8), 0, stream,
                     p.Wi + (size_t)1024*512, WiT + (size_t)512*1024, 1024, 512);

  hipLaunchKernelGGL(enc_gemm, dim3(DMn/128, 2048/128), dim3(256), 0, stream,
                     p.ids, p.emb, p.W_enc, p.b_enc, encX);
  hipLaunchKernelGGL(lif_scan, dim3(64), dim3(256), 0, stream, encX);

  hipLaunchKernelGGL(snn_scan, dim3(NWG), dim3(TPB), 0, stream, p, ws);

  hipLaunchKernelGGL(out_gemm, dim3(Vn/128, 2048/128), dim3(256), 0, stream,
                     hs, Wo, bo, (float*)d_out);
}

// Round 7
// 5233.104 us; speedup vs baseline: 11.3107x; 1.1867x over previous
//
#include <hip/hip_runtime.h>
#include <math.h>

#define NWG 256
#define TPB 256

typedef float v4f __attribute__((ext_vector_type(4)));

constexpr int Bn = 16, Sn = 128, Vn = 32000, DMn = 1024, DSn = 512;
constexpr float DECAYc = 0.6065306597126334f;  // exp(-1/tau), tau=2
constexpr float THRc = 1.0f, EPSc = 1e-5f;

// ---- workspace byte offsets ----
constexpr size_t OF_FLAGS  = 0;                                   // 256 WGs * 4KB
constexpr size_t OF_STATES = (size_t)256*4096;                    // [2][16][512]
constexpr size_t OF_E0     = OF_STATES + (size_t)2*16*512*4;      // [16][1024]
constexpr size_t OF_E1     = OF_E0 + (size_t)16*1024*4;
constexpr size_t OF_ENCX   = OF_E1 + (size_t)16*1024*4;           // [128][16][1024] raw enc GEMM
constexpr size_t OF_HS     = OF_ENCX + (size_t)128*16*1024*4;     // [128][16][512]
constexpr size_t OF_WGT    = OF_HS + (size_t)128*16*512*4;        // WgT [2][1024][512]
constexpr size_t OF_WIT    = OF_WGT + (size_t)2*1024*512*4;       // WiT [2][512][1024]
constexpr size_t INIT_BYTES = OF_E0;   // zero flags + states

struct SP {
  const int* ids; const float* emb;
  const float* W_enc; const float* b_enc;
  const float* ln_s_g; const float* ln_s_b;
  const float* Wg; const float* bg;
  const float* ln_e_g; const float* ln_e_b;
  const float* Wi; const float* bi;
};

// LLC-coherent (L1+L2 bypass) accesses: no fences needed anywhere.
__device__ __forceinline__ float ld_cg(const float* p) {
  return __hip_atomic_load(p, __ATOMIC_RELAXED, __HIP_MEMORY_SCOPE_AGENT);
}
__device__ __forceinline__ void st_cg(float* p, float v) {
  __hip_atomic_store(p, v, __ATOMIC_RELAXED, __HIP_MEMORY_SCOPE_AGENT);
}
__device__ __forceinline__ int ld_flag(const int* p) {
  return __hip_atomic_load(p, __ATOMIC_RELAXED, __HIP_MEMORY_SCOPE_AGENT);
}
__device__ __forceinline__ void st_flag(int* p, int v) {
  __hip_atomic_store(p, v, __ATOMIC_RELAXED, __HIP_MEMORY_SCOPE_AGENT);
}

// 16B-chunk XOR swizzle (involution) for conflict-reduced strided b128 LDS access
__device__ __forceinline__ int swc(int c) { return c ^ ((c >> 3) & 7); }

// one butterfly reduce-scatter step: SZ live values -> SZ/2, partner lane ^M.
template<int SZ>
__device__ __forceinline__ void bstep(float* v, bool up, int M) {
  #pragma unroll
  for (int q = 0; q < SZ/2; q++) {
    float lo = v[q], hi = v[q + SZ/2];
    float send = up ? lo : hi;
    float recv = __shfl_xor(send, M);
    v[q] = (up ? hi : lo) + recv;
  }
}

// One fused step (group owns batch rows grp*4..grp*4+3); identical data path
// to the verified R5 kernel. ROP: 1 gen-first (bottom = inline encoder LIF of
// raw enc GEMM output), 2 gen-cont (bottom=btreg), 3 inf (streg+=spike->stw).
// Result per lane after butterfly:
//   OPW==8: o_i=(l>>3)&7, b_loc=(l>>1)&3   (x2 duplicate over l&1)
//   OPW==4: o_i=(l>>4)&3, b_loc=(l>>2)&3   (x4 duplicate over l&3)
template<int K, int NO, int ROP>
__device__ __forceinline__ void step_fn(
    const float* __restrict__ WT,   // [O][K] transposed weights
    const float* __restrict__ bias,
    const float* __restrict__ lng, const float* __restrict__ lnb,
    const float* __restrict__ src,  // [16][K] rows (LLC-coherent)
    float* __restrict__ mreg, float* __restrict__ btreg, float* __restrict__ streg,
    float* __restrict__ encmem, const float* __restrict__ encrow,
    float* __restrict__ errw, float* __restrict__ stw, float* __restrict__ hsw,
    int o0, int grp, float* X, int tid)
{
  constexpr int Kc = K / 64, KC4 = Kc / 4, OPW = NO / 4, NV = 4 * OPW;
  const int w = tid >> 6, l = tid & 63;
  const int o_i   = (OPW == 8) ? ((l >> 3) & 7) : ((l >> 4) & 3);
  const int b_loc = (OPW == 8) ? ((l >> 1) & 3) : ((l >> 2) & 3);
  const int o  = o0 + w*OPW + o_i;
  const int bg = grp*4 + b_loc;

  // ---- inline encoder LIF (gen it==0): bottom spike from raw enc GEMM ----
  float eEv = 0.f;
  if (ROP == 1) {
    const float ex = encrow[(size_t)bg*DMn + o];     // token-static, cached
    const float emt = encmem[0]*DECAYc + ex;
    const float esp = (emt >= THRc) ? 1.f : 0.f;
    encmem[0] = emt * (1.f - esp);
    eEv = esp;
  }

  // ---- W prefetch: lane l loads its k-slice of the wave's o columns (L2) ----
  float wreg[Kc][OPW];
  #pragma unroll
  for (int i = 0; i < OPW; i++) {
    const v4f* wp = (const v4f*)(WT + (size_t)(o0 + w*OPW + i)*K + l*Kc);
    #pragma unroll
    for (int q = 0; q < KC4; q++) {
      v4f v = wp[q];
      #pragma unroll
      for (int e = 0; e < 4; e++) wreg[q*4 + e][i] = v[e];
    }
  }

  // ---- stage + LayerNorm: wave w handles group row w ----
  {
    v4f xr[KC4];
    const float* sp = src + (size_t)(grp*4 + w)*K + l*Kc;
    #pragma unroll
    for (int q = 0; q < KC4; q++)
      asm volatile("global_load_dwordx4 %0, %1, off sc0 sc1"
                   : "=v"(xr[q]) : "v"(sp + 4*q));
    asm volatile("s_waitcnt vmcnt(0)" ::: "memory");
    __builtin_amdgcn_sched_barrier(0);
    float s1 = 0.f;
    #pragma unroll
    for (int q = 0; q < KC4; q++)
      #pragma unroll
      for (int e = 0; e < 4; e++) s1 += xr[q][e];
    #pragma unroll
    for (int off = 32; off; off >>= 1) s1 += __shfl_xor(s1, off);
    const float mean = s1 * (1.0f / K);
    float s2 = 0.f;
    #pragma unroll
    for (int q = 0; q < KC4; q++)
      #pragma unroll
      for (int e = 0; e < 4; e++) { float d = xr[q][e] - mean; s2 += d*d; }
    #pragma unroll
    for (int off = 32; off; off >>= 1) s2 += __shfl_xor(s2, off);
    const float rstd = 1.0f / sqrtf(s2 * (1.0f / K) + EPSc);
    #pragma unroll
    for (int q = 0; q < KC4; q++) {
      v4f ov;
      #pragma unroll
      for (int e = 0; e < 4; e++) {
        const int k = l*Kc + q*4 + e;
        ov[e] = (xr[q][e] - mean) * rstd * lng[k] + lnb[k];
      }
      *(v4f*)(X + w*K + (swc(l*KC4 + q) << 2)) = ov;
    }
  }
  __syncthreads();

  // ---- GEMM partials over lane-local K slice; v[i*4+b] ----
  int xoff[KC4];
  #pragma unroll
  for (int q = 0; q < KC4; q++) xoff[q] = swc(l*KC4 + q) << 2;
  float v[NV];
  #pragma unroll
  for (int n = 0; n < NV; n++) v[n] = 0.f;
  #pragma unroll
  for (int b = 0; b < 4; b++) {
    v4f xv[KC4];
    #pragma unroll
    for (int q = 0; q < KC4; q++) xv[q] = *(const v4f*)(X + b*K + xoff[q]);
    #pragma unroll
    for (int i = 0; i < OPW; i++) {
      float a = v[i*4 + b];
      #pragma unroll
      for (int q = 0; q < KC4; q++)
        #pragma unroll
        for (int e = 0; e < 4; e++) a = fmaf(xv[q][e], wreg[q*4 + e][i], a);
      v[i*4 + b] = a;
    }
  }

  // ---- butterfly reduce-scatter over the 64-way K split ----
  if (OPW == 8) {
    bstep<32>(v, (l & 32) != 0, 32);
    bstep<16>(v, (l & 16) != 0, 16);
    bstep<8> (v, (l &  8) != 0,  8);
    bstep<4> (v, (l &  4) != 0,  4);
    bstep<2> (v, (l &  2) != 0,  2);
    v[0] += __shfl_xor(v[0], 1);           // lanes l,l^1 duplicate
  } else {
    bstep<16>(v, (l & 32) != 0, 32);
    bstep<8> (v, (l & 16) != 0, 16);
    bstep<4> (v, (l &  8) != 0,  8);
    bstep<2> (v, (l &  4) != 0,  4);
    v[0] += __shfl_xor(v[0], 2);           // 4-way duplicate
    v[0] += __shfl_xor(v[0], 1);
  }

  // ---- bias + LIF + outputs ----
  const float val = v[0] + bias[o];
  const float mt = mreg[0] * DECAYc + val;
  const float spk = (mt >= THRc) ? 1.f : 0.f;
  mreg[0] = mt * (1.f - spk);
  if (ROP == 1 || ROP == 2) {
    const float ne = ((ROP == 1) ? eEv : btreg[0]) - spk;
    btreg[0] = ne;
    if ((l & 1) == 0) st_cg(errw + (size_t)bg*DMn + o, ne);
  } else {
    const float ns = streg[0] + spk;
    streg[0] = ns;
    if ((l & 3) == 0) {
      st_cg(stw + (size_t)bg*DSn + o, ns);
      if (hsw) hsw[(size_t)bg*DSn + o] = ns;
    }
  }
}

// Producer/consumer handshake pieces (same mechanism as the verified gbar,
// only the wait-set differs). Publish: drain my stores, WG barrier, tid0 flag.
__device__ __forceinline__ void publish(int* myflag, int tid, int epoch) {
  asm volatile("s_waitcnt vmcnt(0)" ::: "memory");
  __syncthreads();
  if (tid == 0) st_flag(myflag, epoch);
}
// Wait: 32 lanes poll the other half's 32 flags until >= target, then gate WG.
__device__ __forceinline__ void waithalf(const int* othf, int tid, int target) {
  if (tid < 32) {
    while (ld_flag(othf + tid*1024) < target) { }
  }
  asm volatile("" ::: "memory");
  __syncthreads();
}

__global__ void __launch_bounds__(TPB, 1) snn_scan(SP p, char* __restrict__ ws)
{
  __shared__ float X[21504];       // 84 KiB -> 1 WG/CU (co-residency, proven R5)
  const int wgg = blockIdx.x, tid = threadIdx.x;
  const int grp = wgg >> 6, wgl = wgg & 63;
  int* flags  = (int*)(ws + OF_FLAGS);
  int* myflag = flags + (size_t)wgg*1024;
  float* states = (float*)(ws + OF_STATES);
  float* e0     = (float*)(ws + OF_E0);
  float* e1     = (float*)(ws + OF_E1);
  const float* encX = (const float*)(ws + OF_ENCX);
  float* hs     = (float*)(ws + OF_HS);
  const float* WgT = (const float*)(ws + OF_WGT);
  const float* WiT = (const float*)(ws + OF_WIT);
  float* ebuf[2] = { e0, e1 };

  if (wgl < 32) {
    // ---------------- generative pipeline ----------------
    const int* othf = flags + (size_t)(grp*64 + 32)*1024;   // inf flags
    float encMem = 0.f, btReg = 0.f, genMem0 = 0.f, genMem1 = 0.f;
    const int o0 = wgl * 32;
    for (int s = 0; s < Sn; s++) {
      for (int it = 0; it < 8; it++) {
        const int j = it & 1;
        waithalf(othf, tid, s*8 + it - 1);   // I(s,it-2) done (WAR+RAW)
        if (it == 0)
          step_fn<512,32,1>(WgT, p.bg, p.ln_s_g, p.ln_s_b, states,
                            &genMem0, &btReg, nullptr,
                            &encMem, encX + (size_t)s*Bn*DMn,
                            ebuf[0], nullptr, nullptr, o0, grp, X, tid);
        else
          step_fn<512,32,2>(WgT + (size_t)j*DMn*DSn, p.bg + j*DMn,
                            p.ln_s_g + j*DSn, p.ln_s_b + j*DSn,
                            states + (size_t)j*Bn*DSn,
                            j ? &genMem1 : &genMem0, &btReg, nullptr,
                            nullptr, nullptr,
                            ebuf[j], nullptr, nullptr, o0, grp, X, tid);
        publish(myflag, tid, s*8 + it + 1);
      }
    }
  } else {
    // ---------------- inference pipeline ----------------
    const int* othf = flags + (size_t)(grp*64)*1024;        // gen flags
    float infMem0 = 0.f, infMem1 = 0.f, stReg0 = 0.f, stReg1 = 0.f;
    const int o0 = (wgl - 32) * 16;
    for (int s = 0; s < Sn; s++) {
      for (int it = 0; it < 8; it++) {
        const int j = it & 1;
        waithalf(othf, tid, s*8 + it + 1);   // G(s,it) done (RAW+WAR)
        step_fn<1024,16,3>(WiT + (size_t)j*DSn*DMn, p.bi + j*DSn,
                           p.ln_e_g + j*DMn, p.ln_e_b + j*DMn,
                           ebuf[j],
                           j ? &infMem1 : &infMem0, nullptr,
                           j ? &stReg1 : &stReg0,
                           nullptr, nullptr,
                           nullptr, states + (size_t)j*Bn*DSn,
                           (it == 7) ? (hs + (size_t)s*Bn*DSn) : nullptr,
                           o0, grp, X, tid);
        publish(myflag, tid, s*8 + it + 1);
      }
    }
  }
}

// tiled transpose: in [K][O] -> out [O][K]
__global__ void __launch_bounds__(256) transpose_k(
    const float* __restrict__ in, float* __restrict__ out, int K, int O)
{
  __shared__ float t[32][33];
  const int ob = blockIdx.x * 32, kb = blockIdx.y * 32;
  const int x = threadIdx.x, y = threadIdx.y;
  #pragma unroll
  for (int i = 0; i < 32; i += 8) t[y + i][x] = in[(size_t)(kb + y + i)*O + ob + x];
  __syncthreads();
  #pragma unroll
  for (int i = 0; i < 32; i += 8) out[(size_t)(ob + y + i)*K + kb + x] = t[x][y + i];
}

// encX = gather(emb, ids) @ W_enc + b_enc   (M=2048, K=1024, N=1024) — raw, no LIF
__global__ void __launch_bounds__(256) enc_gemm(
    const int* __restrict__ ids, const float* __restrict__ emb,
    const float* __restrict__ We, const float* __restrict__ be,
    float* __restrict__ encX)
{
  __shared__ float As[32][128];
  __shared__ float Bs[32][128];
  __shared__ int rowid[128];
  const int tid = threadIdx.x;
  const int ntile = blockIdx.x * 128;
  const int mtile = blockIdx.y * 128;
  if (tid < 128) {
    int m = mtile + tid;                  // m = s*16 + b
    rowid[tid] = ids[(m & 15)*Sn + (m >> 4)];
  }
  __syncthreads();
  const int tx = tid & 15, ty = tid >> 4;
  float acc[8][8];
  #pragma unroll
  for (int i = 0; i < 8; i++)
    #pragma unroll
    for (int q = 0; q < 8; q++) acc[i][q] = 0.f;

  for (int kb = 0; kb < 32; kb++) {
    #pragma unroll
    for (int r = 0; r < 4; r++) {
      int idx = tid + r*256;
      int m = idx >> 3, kq = idx & 7;
      float4 a = *(const float4*)(emb + (size_t)rowid[m]*DMn + kb*32 + kq*4);
      As[kq*4+0][m] = a.x; As[kq*4+1][m] = a.y;
      As[kq*4+2][m] = a.z; As[kq*4+3][m] = a.w;
    }
    #pragma unroll
    for (int r = 0; r < 4; r++) {
      int idx = tid + r*256;
      int k = idx >> 5, nq = idx & 31;
      *(float4*)(&Bs[k][nq*4]) =
          *(const float4*)(We + (size_t)(kb*32 + k)*DMn + ntile + nq*4);
    }
    __syncthreads();
    #pragma unroll
    for (int k = 0; k < 32; k++) {
      float4 a0 = *(float4*)(&As[k][ty*8]);
      float4 a1 = *(float4*)(&As[k][ty*8+4]);
      float4 b0 = *(float4*)(&Bs[k][tx*8]);
      float4 b1 = *(float4*)(&Bs[k][tx*8+4]);
      float av[8] = {a0.x,a0.y,a0.z,a0.w,a1.x,a1.y,a1.z,a1.w};
      float bv[8] = {b0.x,b0.y,b0.z,b0.w,b1.x,b1.y,b1.z,b1.w};
      #pragma unroll
      for (int i = 0; i < 8; i++)
        #pragma unroll
        for (int q = 0; q < 8; q++) acc[i][q] += av[i]*bv[q];
    }
    __syncthreads();
  }
  const float* bop = be + ntile + tx*8;
  float4 bv0 = *(const float4*)bop;
  float4 bv1 = *(const float4*)(bop + 4);
  #pragma unroll
  for (int i = 0; i < 8; i++) {
    int m = mtile + ty*8 + i;
    float* op = encX + (size_t)m*DMn + ntile + tx*8;
    float4 v0 = make_float4(acc[i][0]+bv0.x, acc[i][1]+bv0.y,
                            acc[i][2]+bv0.z, acc[i][3]+bv0.w);
    float4 v1 = make_float4(acc[i][4]+bv1.x, acc[i][5]+bv1.y,
                            acc[i][6]+bv1.z, acc[i][7]+bv1.w);
    *(float4*)op = v0;
    *(float4*)(op + 4) = v1;
  }
}

// logits = hs @ W_out + b_out, fp32, 128x128 tile, 8x8 microtile
__global__ void __launch_bounds__(256) out_gemm(
    const float* __restrict__ hs, const float* __restrict__ Wo,
    const float* __restrict__ bo, float* __restrict__ out)
{
  __shared__ float As[32][128];
  __shared__ float Bs[32][128];
  const int tid = threadIdx.x;
  const int ntile = blockIdx.x * 128;
  const int mtile = blockIdx.y * 128;
  const int tx = tid & 15, ty = tid >> 4;
  float acc[8][8];
  #pragma unroll
  for (int i = 0; i < 8; i++)
    #pragma unroll
    for (int q = 0; q < 8; q++) acc[i][q] = 0.f;

  for (int kb = 0; kb < 16; kb++) {
    #pragma unroll
    for (int r = 0; r < 4; r++) {
      int idx = tid + r*256;
      int m = idx >> 3, kq = idx & 7;
      float4 a = *(const float4*)(hs + (size_t)(mtile + m)*512 + kb*32 + kq*4);
      As[kq*4+0][m] = a.x; As[kq*4+1][m] = a.y;
      As[kq*4+2][m] = a.z; As[kq*4+3][m] = a.w;
    }
    #pragma unroll
    for (int r = 0; r < 4; r++) {
      int idx = tid + r*256;
      int k = idx >> 5, nq = idx & 31;
      *(float4*)(&Bs[k][nq*4]) =
          *(const float4*)(Wo + (size_t)(kb*32 + k)*Vn + ntile + nq*4);
    }
    __syncthreads();
    #pragma unroll
    for (int k = 0; k < 32; k++) {
      float4 a0 = *(float4*)(&As[k][ty*8]);
      float4 a1 = *(float4*)(&As[k][ty*8+4]);
      float4 b0 = *(float4*)(&Bs[k][tx*8]);
      float4 b1 = *(float4*)(&Bs[k][tx*8+4]);
      float av[8] = {a0.x,a0.y,a0.z,a0.w,a1.x,a1.y,a1.z,a1.w};
      float bv[8] = {b0.x,b0.y,b0.z,b0.w,b1.x,b1.y,b1.z,b1.w};
      #pragma unroll
      for (int i = 0; i < 8; i++)
        #pragma unroll
        for (int q = 0; q < 8; q++) acc[i][q] += av[i]*bv[q];
    }
    __syncthreads();
  }
  const float* bop = bo + ntile + tx*8;
  float4 bv0 = *(const float4*)bop;
  float4 bv1 = *(const float4*)(bop + 4);
  #pragma unroll
  for (int i = 0; i < 8; i++) {
    int m = mtile + ty*8 + i;            // m = s*16 + b
    float* op = out + ((size_t)(m & 15)*Sn + (m >> 4))*Vn + ntile + tx*8;
    float4 v0 = make_float4(acc[i][0]+bv0.x, acc[i][1]+bv0.y,
                            acc[i][2]+bv0.z, acc[i][3]+bv0.w);
    float4 v1 = make_float4(acc[i][4]+bv1.x, acc[i][5]+bv1.y,
                            acc[i][6]+bv1.z, acc[i][7]+bv1.w);
    *(float4*)op = v0;
    *(float4*)(op + 4) = v1;
  }
}

extern "C" void kernel_launch(void* const* d_in, const int* in_sizes, int n_in,
                              void* d_out, int out_size, void* d_ws, size_t ws_size,
                              hipStream_t stream) {
  (void)in_sizes; (void)n_in; (void)out_size; (void)ws_size;
  SP p;
  p.ids    = (const int*)  d_in[0];
  p.emb    = (const float*)d_in[1];
  p.W_enc  = (const float*)d_in[2];
  p.b_enc  = (const float*)d_in[3];
  p.ln_s_g = (const float*)d_in[4];
  p.ln_s_b = (const float*)d_in[5];
  p.Wg     = (const float*)d_in[6];
  p.bg     = (const float*)d_in[7];
  p.ln_e_g = (const float*)d_in[8];
  p.ln_e_b = (const float*)d_in[9];
  p.Wi     = (const float*)d_in[10];
  p.bi     = (const float*)d_in[11];
  const float* Wo = (const float*)d_in[12];
  const float* bo = (const float*)d_in[13];

  char* ws = (char*)d_ws;
  float* WgT  = (float*)(ws + OF_WGT);
  float* WiT  = (float*)(ws + OF_WIT);
  float* encX = (float*)(ws + OF_ENCX);
  float* hs   = (float*)(ws + OF_HS);

  hipMemsetAsync(ws, 0, INIT_BYTES, stream);   // flags + states = 0

  hipLaunchKernelGGL(transpose_k, dim3(32, 16), dim3(32, 8), 0, stream,
                     p.Wg, WgT, 512, 1024);
  hipLaunchKernelGGL(transpose_k, dim3(32, 16), dim3(32, 8), 0, stream,
                     p.Wg + (size_t)512*1024, WgT + (size_t)1024*512, 512, 1024);
  hipLaunchKernelGGL(transpose_k, dim3(16, 32), dim3(32, 8), 0, stream,
                     p.Wi, WiT, 1024, 512);
  hipLaunchKernelGGL(transpose_k, dim3(16, 32), dim3(32, 8), 0, stream,
                     p.Wi + (size_t)1024*512, WiT + (size_t)512*1024, 1024, 512);

  hipLaunchKernelGGL(enc_gemm, dim3(DMn/128, 2048/128), dim3(256), 0, stream,
                     p.ids, p.emb, p.W_enc, p.b_enc, encX);

  hipLaunchKernelGGL(snn_scan, dim3(NWG), dim3(TPB), 0, stream, p, ws);

  hipLaunchKernelGGL(out_gemm, dim3(Vn/128, 2048/128), dim3(256), 0, stream,
                     hs, Wo, bo, (float*)d_out);
}

// Round 8
// 4527.661 us; speedup vs baseline: 13.0730x; 1.1558x over previous
//
#include <hip/hip_runtime.h>
#include <math.h>

#define NWG 256
#define TPB 256

typedef float v4f __attribute__((ext_vector_type(4)));

constexpr int Bn = 16, Sn = 128, Vn = 32000, DMn = 1024, DSn = 512;
constexpr float DECAYc = 0.6065306597126334f;  // exp(-1/tau), tau=2
constexpr float THRc = 1.0f, EPSc = 1e-5f;

// ---- workspace byte offsets (identical to R7) ----
constexpr size_t OF_FLAGS  = 0;                                   // 256 WGs * 4KB
constexpr size_t OF_STATES = (size_t)256*4096;                    // [2][16][512]
constexpr size_t OF_E0     = OF_STATES + (size_t)2*16*512*4;      // [16][1024]
constexpr size_t OF_E1     = OF_E0 + (size_t)16*1024*4;
constexpr size_t OF_ENCX   = OF_E1 + (size_t)16*1024*4;           // [128][16][1024] raw enc GEMM
constexpr size_t OF_HS     = OF_ENCX + (size_t)128*16*1024*4;     // [128][16][512]
constexpr size_t OF_WGT    = OF_HS + (size_t)128*16*512*4;        // WgT [2][1024][512]
constexpr size_t OF_WIT    = OF_WGT + (size_t)2*1024*512*4;       // WiT [2][512][1024]
constexpr size_t INIT_BYTES = OF_E0;   // zero flags + states

struct SP {
  const int* ids; const float* emb;
  const float* W_enc; const float* b_enc;
  const float* ln_s_g; const float* ln_s_b;
  const float* Wg; const float* bg;
  const float* ln_e_g; const float* ln_e_b;
  const float* Wi; const float* bi;
};

// LLC-coherent (L1+L2 bypass) accesses: no fences needed anywhere.
__device__ __forceinline__ void st_cg(float* p, float v) {
  __hip_atomic_store(p, v, __ATOMIC_RELAXED, __HIP_MEMORY_SCOPE_AGENT);
}
__device__ __forceinline__ int ld_flag(const int* p) {
  return __hip_atomic_load(p, __ATOMIC_RELAXED, __HIP_MEMORY_SCOPE_AGENT);
}
__device__ __forceinline__ void st_flag(int* p, int v) {
  __hip_atomic_store(p, v, __ATOMIC_RELAXED, __HIP_MEMORY_SCOPE_AGENT);
}

// 16B-chunk XOR swizzle (involution) for conflict-reduced strided b128 LDS access
__device__ __forceinline__ int swc(int c) { return c ^ ((c >> 3) & 7); }

// one butterfly reduce-scatter step: SZ live values -> SZ/2, partner lane ^M.
template<int SZ>
__device__ __forceinline__ void bstep(float* v, bool up, int M) {
  #pragma unroll
  for (int q = 0; q < SZ/2; q++) {
    float lo = v[q], hi = v[q + SZ/2];
    float send = up ? lo : hi;
    float recv = __shfl_xor(send, M);
    v[q] = (up ? hi : lo) + recv;
  }
}

// publish: drain my stores, WG barrier, tid0 flag (proven R7 mechanism)
__device__ __forceinline__ void publish(int* myflag, int tid, int epoch) {
  asm volatile("s_waitcnt vmcnt(0)" ::: "memory");
  __syncthreads();
  if (tid == 0) st_flag(myflag, epoch);
}
// wait: 32 lanes poll the other half's 32 flags until >= target, then gate WG.
__device__ __forceinline__ void waithalf(const int* othf, int tid, int target) {
  if (tid < 32) {
    while (ld_flag(othf + tid*1024) < target) { }
  }
  asm volatile("" ::: "memory");
  __syncthreads();
}

// ---------------- gen step: K=512, 32 o/WG (8 o/wave) ----------------
// FIRST: bottom = eEv (inline-encoded spike); else bottom = btReg chain.
template<bool FIRST>
__device__ __forceinline__ void gen_step(
    const float (&wreg)[8][8], const float (&lg)[8], const float (&lb)[8],
    float biasv, const float* __restrict__ src,   // states[j]
    float& mreg, float& btReg, float eEv,
    float* __restrict__ errw, int o, int bg, int grp, float* X, int tid)
{
  const int w = tid >> 6, l = tid & 63;
  // stage + LN: wave w handles group row w (Kc=8 per lane)
  v4f xr0, xr1;
  const float* sp = src + (size_t)(grp*4 + w)*DSn + l*8;
  asm volatile("global_load_dwordx4 %0, %1, off sc0 sc1" : "=v"(xr0) : "v"(sp));
  asm volatile("global_load_dwordx4 %0, %1, off sc0 sc1" : "=v"(xr1) : "v"(sp + 4));
  asm volatile("s_waitcnt vmcnt(0)" ::: "memory");
  __builtin_amdgcn_sched_barrier(0);
  float s1 = 0.f;
  #pragma unroll
  for (int e = 0; e < 4; e++) { s1 += xr0[e]; s1 += xr1[e]; }
  #pragma unroll
  for (int off = 32; off; off >>= 1) s1 += __shfl_xor(s1, off);
  const float mean = s1 * (1.0f / 512.0f);
  float s2 = 0.f;
  #pragma unroll
  for (int e = 0; e < 4; e++) {
    float d0 = xr0[e] - mean; s2 += d0*d0;
    float d1 = xr1[e] - mean; s2 += d1*d1;
  }
  #pragma unroll
  for (int off = 32; off; off >>= 1) s2 += __shfl_xor(s2, off);
  const float rstd = 1.0f / sqrtf(s2 * (1.0f / 512.0f) + EPSc);
  v4f ov0, ov1;
  #pragma unroll
  for (int e = 0; e < 4; e++) {
    ov0[e] = (xr0[e] - mean)*rstd*lg[e]   + lb[e];
    ov1[e] = (xr1[e] - mean)*rstd*lg[4+e] + lb[4+e];
  }
  *(v4f*)(X + w*DSn + (swc(l*2 + 0) << 2)) = ov0;
  *(v4f*)(X + w*DSn + (swc(l*2 + 1) << 2)) = ov1;
  __syncthreads();
  // GEMM partials (same FMA order as R7)
  const int xo0 = swc(l*2 + 0) << 2, xo1 = swc(l*2 + 1) << 2;
  float v[32];
  #pragma unroll
  for (int n = 0; n < 32; n++) v[n] = 0.f;
  #pragma unroll
  for (int b = 0; b < 4; b++) {
    v4f x0 = *(const v4f*)(X + b*DSn + xo0);
    v4f x1 = *(const v4f*)(X + b*DSn + xo1);
    #pragma unroll
    for (int i = 0; i < 8; i++) {
      float a = v[i*4 + b];
      #pragma unroll
      for (int e = 0; e < 4; e++) a = fmaf(x0[e], wreg[e][i], a);
      #pragma unroll
      for (int e = 0; e < 4; e++) a = fmaf(x1[e], wreg[4+e][i], a);
      v[i*4 + b] = a;
    }
  }
  // butterfly reduce-scatter (NV=32)
  bstep<32>(v, (l & 32) != 0, 32);
  bstep<16>(v, (l & 16) != 0, 16);
  bstep<8> (v, (l &  8) != 0,  8);
  bstep<4> (v, (l &  4) != 0,  4);
  bstep<2> (v, (l &  2) != 0,  2);
  v[0] += __shfl_xor(v[0], 1);
  // bias + LIF + err store
  const float val = v[0] + biasv;
  const float mt = mreg * DECAYc + val;
  const float spk = (mt >= THRc) ? 1.f : 0.f;
  mreg = mt * (1.f - spk);
  const float ne = (FIRST ? eEv : btReg) - spk;
  btReg = ne;
  if ((l & 1) == 0) st_cg(errw + (size_t)bg*DMn + o, ne);
}

// ---------------- inf step: K=1024, 16 o/WG (4 o/wave) ----------------
__device__ __forceinline__ void inf_step(
    const float (&wreg)[16][4], const float (&lg)[16], const float (&lb)[16],
    float biasv, const float* __restrict__ src,   // err[j]
    float& mreg, float& streg,
    float* __restrict__ stw, float* __restrict__ hsw,
    int o, int bg, int grp, float* X, int tid)
{
  const int w = tid >> 6, l = tid & 63;
  v4f xr[4];
  const float* sp = src + (size_t)(grp*4 + w)*DMn + l*16;
  #pragma unroll
  for (int q = 0; q < 4; q++)
    asm volatile("global_load_dwordx4 %0, %1, off sc0 sc1" : "=v"(xr[q]) : "v"(sp + 4*q));
  asm volatile("s_waitcnt vmcnt(0)" ::: "memory");
  __builtin_amdgcn_sched_barrier(0);
  float s1 = 0.f;
  #pragma unroll
  for (int q = 0; q < 4; q++)
    #pragma unroll
    for (int e = 0; e < 4; e++) s1 += xr[q][e];
  #pragma unroll
  for (int off = 32; off; off >>= 1) s1 += __shfl_xor(s1, off);
  const float mean = s1 * (1.0f / 1024.0f);
  float s2 = 0.f;
  #pragma unroll
  for (int q = 0; q < 4; q++)
    #pragma unroll
    for (int e = 0; e < 4; e++) { float d = xr[q][e] - mean; s2 += d*d; }
  #pragma unroll
  for (int off = 32; off; off >>= 1) s2 += __shfl_xor(s2, off);
  const float rstd = 1.0f / sqrtf(s2 * (1.0f / 1024.0f) + EPSc);
  #pragma unroll
  for (int q = 0; q < 4; q++) {
    v4f ov;
    #pragma unroll
    for (int e = 0; e < 4; e++)
      ov[e] = (xr[q][e] - mean)*rstd*lg[q*4+e] + lb[q*4+e];
    *(v4f*)(X + w*DMn + (swc(l*4 + q) << 2)) = ov;
  }
  __syncthreads();
  int xo[4];
  #pragma unroll
  for (int q = 0; q < 4; q++) xo[q] = swc(l*4 + q) << 2;
  float v[16];
  #pragma unroll
  for (int n = 0; n < 16; n++) v[n] = 0.f;
  #pragma unroll
  for (int b = 0; b < 4; b++) {
    v4f xv[4];
    #pragma unroll
    for (int q = 0; q < 4; q++) xv[q] = *(const v4f*)(X + b*DMn + xo[q]);
    #pragma unroll
    for (int i = 0; i < 4; i++) {
      float a = v[i*4 + b];
      #pragma unroll
      for (int q = 0; q < 4; q++)
        #pragma unroll
        for (int e = 0; e < 4; e++) a = fmaf(xv[q][e], wreg[q*4+e][i], a);
      v[i*4 + b] = a;
    }
  }
  bstep<16>(v, (l & 32) != 0, 32);
  bstep<8> (v, (l & 16) != 0, 16);
  bstep<4> (v, (l &  8) != 0,  8);
  bstep<2> (v, (l &  4) != 0,  4);
  v[0] += __shfl_xor(v[0], 2);
  v[0] += __shfl_xor(v[0], 1);
  const float val = v[0] + biasv;
  const float mt = mreg * DECAYc + val;
  const float spk = (mt >= THRc) ? 1.f : 0.f;
  mreg = mt * (1.f - spk);
  const float ns = streg + spk;
  streg = ns;
  if ((l & 3) == 0) {
    st_cg(stw + (size_t)bg*DSn + o, ns);
    if (hsw) hsw[(size_t)bg*DSn + o] = ns;
  }
}

__global__ void __launch_bounds__(TPB, 1) snn_scan(SP p, char* __restrict__ ws)
{
  extern __shared__ float X[];     // 84 KiB dynamic -> 1 WG/CU co-residency
  const int wgg = blockIdx.x, tid = threadIdx.x;
  const int grp = wgg >> 6, wgl = wgg & 63;
  const int w = tid >> 6, l = tid & 63;
  int* flags  = (int*)(ws + OF_FLAGS);
  int* myflag = flags + (size_t)wgg*1024;
  float* states = (float*)(ws + OF_STATES);
  float* e0     = (float*)(ws + OF_E0);
  float* e1     = (float*)(ws + OF_E1);
  const float* encX = (const float*)(ws + OF_ENCX);
  float* hs     = (float*)(ws + OF_HS);
  const float* WgT = (const float*)(ws + OF_WGT);
  const float* WiT = (const float*)(ws + OF_WIT);
  float* st0 = states;
  float* st1 = states + (size_t)Bn*DSn;

  if (wgl < 32) {
    // ---------------- generative pipeline ----------------
    const int* othf = flags + (size_t)(grp*64 + 32)*1024;   // inf flags
    const int o0 = wgl * 32;
    const int o_i = (l >> 3) & 7, b_loc = (l >> 1) & 3;
    const int o = o0 + w*8 + o_i, bg = grp*4 + b_loc;
    // ---- preload both W slices + LN params + biases into registers ----
    float wA[8][8], wB[8][8];
    #pragma unroll
    for (int i = 0; i < 8; i++) {
      const v4f* pa = (const v4f*)(WgT + (size_t)(o0 + w*8 + i)*DSn + l*8);
      const v4f* pb = (const v4f*)(WgT + (size_t)DMn*DSn + (size_t)(o0 + w*8 + i)*DSn + l*8);
      v4f a0 = pa[0], a1 = pa[1], b0 = pb[0], b1 = pb[1];
      #pragma unroll
      for (int e = 0; e < 4; e++) {
        wA[e][i] = a0[e]; wA[4+e][i] = a1[e];
        wB[e][i] = b0[e]; wB[4+e][i] = b1[e];
      }
    }
    float lgA[8], lbA[8], lgB[8], lbB[8];
    {
      const v4f* g0 = (const v4f*)(p.ln_s_g + l*8);
      const v4f* c0 = (const v4f*)(p.ln_s_b + l*8);
      const v4f* g1 = (const v4f*)(p.ln_s_g + DSn + l*8);
      const v4f* c1 = (const v4f*)(p.ln_s_b + DSn + l*8);
      v4f ga = g0[0], gb = g0[1], ba = c0[0], bb = c0[1];
      v4f gc = g1[0], gd = g1[1], bc = c1[0], bd = c1[1];
      #pragma unroll
      for (int e = 0; e < 4; e++) {
        lgA[e] = ga[e]; lgA[4+e] = gb[e]; lbA[e] = ba[e]; lbA[4+e] = bb[e];
        lgB[e] = gc[e]; lgB[4+e] = gd[e]; lbB[e] = bc[e]; lbB[4+e] = bd[e];
      }
    }
    const float biasA = p.bg[o], biasB = p.bg[DMn + o];
    float encMem = 0.f, btReg = 0.f, genMemA = 0.f, genMemB = 0.f;

    for (int s = 0; s < Sn; s++) {
      const int s8 = s*8;
      // inline encoder LIF input hoisted before the wait (token-static)
      const float ex = encX[(size_t)s*Bn*DMn + (size_t)bg*DMn + o];
      const float emt = encMem*DECAYc + ex;
      const float esp = (emt >= THRc) ? 1.f : 0.f;
      encMem = emt * (1.f - esp);
      waithalf(othf, tid, s8 - 1);
      gen_step<true >(wA, lgA, lbA, biasA, st0, genMemA, btReg, esp, e0, o, bg, grp, X, tid);
      publish(myflag, tid, s8 + 1);
      waithalf(othf, tid, s8 + 0);
      gen_step<false>(wB, lgB, lbB, biasB, st1, genMemB, btReg, 0.f, e1, o, bg, grp, X, tid);
      publish(myflag, tid, s8 + 2);
      waithalf(othf, tid, s8 + 1);
      gen_step<false>(wA, lgA, lbA, biasA, st0, genMemA, btReg, 0.f, e0, o, bg, grp, X, tid);
      publish(myflag, tid, s8 + 3);
      waithalf(othf, tid, s8 + 2);
      gen_step<false>(wB, lgB, lbB, biasB, st1, genMemB, btReg, 0.f, e1, o, bg, grp, X, tid);
      publish(myflag, tid, s8 + 4);
      waithalf(othf, tid, s8 + 3);
      gen_step<false>(wA, lgA, lbA, biasA, st0, genMemA, btReg, 0.f, e0, o, bg, grp, X, tid);
      publish(myflag, tid, s8 + 5);
      waithalf(othf, tid, s8 + 4);
      gen_step<false>(wB, lgB, lbB, biasB, st1, genMemB, btReg, 0.f, e1, o, bg, grp, X, tid);
      publish(myflag, tid, s8 + 6);
      waithalf(othf, tid, s8 + 5);
      gen_step<false>(wA, lgA, lbA, biasA, st0, genMemA, btReg, 0.f, e0, o, bg, grp, X, tid);
      publish(myflag, tid, s8 + 7);
      waithalf(othf, tid, s8 + 6);
      gen_step<false>(wB, lgB, lbB, biasB, st1, genMemB, btReg, 0.f, e1, o, bg, grp, X, tid);
      publish(myflag, tid, s8 + 8);
    }
  } else {
    // ---------------- inference pipeline ----------------
    const int* othf = flags + (size_t)(grp*64)*1024;        // gen flags
    const int o0 = (wgl - 32) * 16;
    const int o_i = (l >> 4) & 3, b_loc = (l >> 2) & 3;
    const int o = o0 + w*4 + o_i, bg = grp*4 + b_loc;
    float wA[16][4], wB[16][4];
    #pragma unroll
    for (int i = 0; i < 4; i++) {
      const v4f* pa = (const v4f*)(WiT + (size_t)(o0 + w*4 + i)*DMn + l*16);
      const v4f* pb = (const v4f*)(WiT + (size_t)DSn*DMn + (size_t)(o0 + w*4 + i)*DMn + l*16);
      #pragma unroll
      for (int q = 0; q < 4; q++) {
        v4f a = pa[q], b = pb[q];
        #pragma unroll
        for (int e = 0; e < 4; e++) { wA[q*4+e][i] = a[e]; wB[q*4+e][i] = b[e]; }
      }
    }
    float lgA[16], lbA[16], lgB[16], lbB[16];
    {
      const v4f* g0 = (const v4f*)(p.ln_e_g + l*16);
      const v4f* c0 = (const v4f*)(p.ln_e_b + l*16);
      const v4f* g1 = (const v4f*)(p.ln_e_g + DMn + l*16);
      const v4f* c1 = (const v4f*)(p.ln_e_b + DMn + l*16);
      #pragma unroll
      for (int q = 0; q < 4; q++) {
        v4f ga = g0[q], ba = c0[q], gb = g1[q], bb = c1[q];
        #pragma unroll
        for (int e = 0; e < 4; e++) {
          lgA[q*4+e] = ga[e]; lbA[q*4+e] = ba[e];
          lgB[q*4+e] = gb[e]; lbB[q*4+e] = bb[e];
        }
      }
    }
    const float biasA = p.bi[o], biasB = p.bi[DSn + o];
    float infMemA = 0.f, infMemB = 0.f, stRegA = 0.f, stRegB = 0.f;

    for (int s = 0; s < Sn; s++) {
      const int s8 = s*8;
      waithalf(othf, tid, s8 + 1);
      inf_step(wA, lgA, lbA, biasA, e0, infMemA, stRegA, st0, nullptr, o, bg, grp, X, tid);
      publish(myflag, tid, s8 + 1);
      waithalf(othf, tid, s8 + 2);
      inf_step(wB, lgB, lbB, biasB, e1, infMemB, stRegB, st1, nullptr, o, bg, grp, X, tid);
      publish(myflag, tid, s8 + 2);
      waithalf(othf, tid, s8 + 3);
      inf_step(wA, lgA, lbA, biasA, e0, infMemA, stRegA, st0, nullptr, o, bg, grp, X, tid);
      publish(myflag, tid, s8 + 3);
      waithalf(othf, tid, s8 + 4);
      inf_step(wB, lgB, lbB, biasB, e1, infMemB, stRegB, st1, nullptr, o, bg, grp, X, tid);
      publish(myflag, tid, s8 + 4);
      waithalf(othf, tid, s8 + 5);
      inf_step(wA, lgA, lbA, biasA, e0, infMemA, stRegA, st0, nullptr, o, bg, grp, X, tid);
      publish(myflag, tid, s8 + 5);
      waithalf(othf, tid, s8 + 6);
      inf_step(wB, lgB, lbB, biasB, e1, infMemB, stRegB, st1, nullptr, o, bg, grp, X, tid);
      publish(myflag, tid, s8 + 6);
      waithalf(othf, tid, s8 + 7);
      inf_step(wA, lgA, lbA, biasA, e0, infMemA, stRegA, st0, nullptr, o, bg, grp, X, tid);
      publish(myflag, tid, s8 + 7);
      waithalf(othf, tid, s8 + 8);
      inf_step(wB, lgB, lbB, biasB, e1, infMemB, stRegB, st1,
               hs + (size_t)s*Bn*DSn, o, bg, grp, X, tid);
      publish(myflag, tid, s8 + 8);
    }
  }
}

// tiled transpose: in [K][O] -> out [O][K]
__global__ void __launch_bounds__(256) transpose_k(
    const float* __restrict__ in, float* __restrict__ out, int K, int O)
{
  __shared__ float t[32][33];
  const int ob = blockIdx.x * 32, kb = blockIdx.y * 32;
  const int x = threadIdx.x, y = threadIdx.y;
  #pragma unroll
  for (int i = 0; i < 32; i += 8) t[y + i][x] = in[(size_t)(kb + y + i)*O + ob + x];
  __syncthreads();
  #pragma unroll
  for (int i = 0; i < 32; i += 8) out[(size_t)(ob + y + i)*K + kb + x] = t[x][y + i];
}

// encX = gather(emb, ids) @ W_enc + b_enc   (M=2048, K=1024, N=1024) — raw, no LIF
__global__ void __launch_bounds__(256) enc_gemm(
    const int* __restrict__ ids, const float* __restrict__ emb,
    const float* __restrict__ We, const float* __restrict__ be,
    float* __restrict__ encX)
{
  __shared__ float As[32][128];
  __shared__ float Bs[32][128];
  __shared__ int rowid[128];
  const int tid = threadIdx.x;
  const int ntile = blockIdx.x * 128;
  const int mtile = blockIdx.y * 128;
  if (tid < 128) {
    int m = mtile + tid;                  // m = s*16 + b
    rowid[tid] = ids[(m & 15)*Sn + (m >> 4)];
  }
  __syncthreads();
  const int tx = tid & 15, ty = tid >> 4;
  float acc[8][8];
  #pragma unroll
  for (int i = 0; i < 8; i++)
    #pragma unroll
    for (int q = 0; q < 8; q++) acc[i][q] = 0.f;

  for (int kb = 0; kb < 32; kb++) {
    #pragma unroll
    for (int r = 0; r < 4; r++) {
      int idx = tid + r*256;
      int m = idx >> 3, kq = idx & 7;
      float4 a = *(const float4*)(emb + (size_t)rowid[m]*DMn + kb*32 + kq*4);
      As[kq*4+0][m] = a.x; As[kq*4+1][m] = a.y;
      As[kq*4+2][m] = a.z; As[kq*4+3][m] = a.w;
    }
    #pragma unroll
    for (int r = 0; r < 4; r++) {
      int idx = tid + r*256;
      int k = idx >> 5, nq = idx & 31;
      *(float4*)(&Bs[k][nq*4]) =
          *(const float4*)(We + (size_t)(kb*32 + k)*DMn + ntile + nq*4);
    }
    __syncthreads();
    #pragma unroll
    for (int k = 0; k < 32; k++) {
      float4 a0 = *(float4*)(&As[k][ty*8]);
      float4 a1 = *(float4*)(&As[k][ty*8+4]);
      float4 b0 = *(float4*)(&Bs[k][tx*8]);
      float4 b1 = *(float4*)(&Bs[k][tx*8+4]);
      float av[8] = {a0.x,a0.y,a0.z,a0.w,a1.x,a1.y,a1.z,a1.w};
      float bv[8] = {b0.x,b0.y,b0.z,b0.w,b1.x,b1.y,b1.z,b1.w};
      #pragma unroll
      for (int i = 0; i < 8; i++)
        #pragma unroll
        for (int q = 0; q < 8; q++) acc[i][q] += av[i]*bv[q];
    }
    __syncthreads();
  }
  const float* bop = be + ntile + tx*8;
  float4 bv0 = *(const float4*)bop;
  float4 bv1 = *(const float4*)(bop + 4);
  #pragma unroll
  for (int i = 0; i < 8; i++) {
    int m = mtile + ty*8 + i;
    float* op = encX + (size_t)m*DMn + ntile + tx*8;
    float4 v0 = make_float4(acc[i][0]+bv0.x, acc[i][1]+bv0.y,
                            acc[i][2]+bv0.z, acc[i][3]+bv0.w);
    float4 v1 = make_float4(acc[i][4]+bv1.x, acc[i][5]+bv1.y,
                            acc[i][6]+bv1.z, acc[i][7]+bv1.w);
    *(float4*)op = v0;
    *(float4*)(op + 4) = v1;
  }
}

// logits = hs @ W_out + b_out, fp32, 128x128 tile, 8x8 microtile
__global__ void __launch_bounds__(256) out_gemm(
    const float* __restrict__ hs, const float* __restrict__ Wo,
    const float* __restrict__ bo, float* __restrict__ out)
{
  __shared__ float As[32][128];
  __shared__ float Bs[32][128];
  const int tid = threadIdx.x;
  const int ntile = blockIdx.x * 128;
  const int mtile = blockIdx.y * 128;
  const int tx = tid & 15, ty = tid >> 4;
  float acc[8][8];
  #pragma unroll
  for (int i = 0; i < 8; i++)
    #pragma unroll
    for (int q = 0; q < 8; q++) acc[i][q] = 0.f;

  for (int kb = 0; kb < 16; kb++) {
    #pragma unroll
    for (int r = 0; r < 4; r++) {
      int idx = tid + r*256;
      int m = idx >> 3, kq = idx & 7;
      float4 a = *(const float4*)(hs + (size_t)(mtile + m)*512 + kb*32 + kq*4);
      As[kq*4+0][m] = a.x; As[kq*4+1][m] = a.y;
      As[kq*4+2][m] = a.z; As[kq*4+3][m] = a.w;
    }
    #pragma unroll
    for (int r = 0; r < 4; r++) {
      int idx = tid + r*256;
      int k = idx >> 5, nq = idx & 31;
      *(float4*)(&Bs[k][nq*4]) =
          *(const float4*)(Wo + (size_t)(kb*32 + k)*Vn + ntile + nq*4);
    }
    __syncthreads();
    #pragma unroll
    for (int k = 0; k < 32; k++) {
      float4 a0 = *(float4*)(&As[k][ty*8]);
      float4 a1 = *(float4*)(&As[k][ty*8+4]);
      float4 b0 = *(float4*)(&Bs[k][tx*8]);
      float4 b1 = *(float4*)(&Bs[k][tx*8+4]);
      float av[8] = {a0.x,a0.y,a0.z,a0.w,a1.x,a1.y,a1.z,a1.w};
      float bv[8] = {b0.x,b0.y,b0.z,b0.w,b1.x,b1.y,b1.z,b1.w};
      #pragma unroll
      for (int i = 0; i < 8; i++)
        #pragma unroll
        for (int q = 0; q < 8; q++) acc[i][q] += av[i]*bv[q];
    }
    __syncthreads();
  }
  const float* bop = bo + ntile + tx*8;
  float4 bv0 = *(const float4*)bop;
  float4 bv1 = *(const float4*)(bop + 4);
  #pragma unroll
  for (int i = 0; i < 8; i++) {
    int m = mtile + ty*8 + i;            // m = s*16 + b
    float* op = out + ((size_t)(m & 15)*Sn + (m >> 4))*Vn + ntile + tx*8;
    float4 v0 = make_float4(acc[i][0]+bv0.x, acc[i][1]+bv0.y,
                            acc[i][2]+bv0.z, acc[i][3]+bv0.w);
    float4 v1 = make_float4(acc[i][4]+bv1.x, acc[i][5]+bv1.y,
                            acc[i][6]+bv1.z, acc[i][7]+bv1.w);
    *(float4*)op = v0;
    *(float4*)(op + 4) = v1;
  }
}

extern "C" void kernel_launch(void* const* d_in, const int* in_sizes, int n_in,
                              void* d_out, int out_size, void* d_ws, size_t ws_size,
                              hipStream_t stream) {
  (void)in_sizes; (void)n_in; (void)out_size; (void)ws_size;
  SP p;
  p.ids    = (const int*)  d_in[0];
  p.emb    = (const float*)d_in[1];
  p.W_enc  = (const float*)d_in[2];
  p.b_enc  = (const float*)d_in[3];
  p.ln_s_g = (const float*)d_in[4];
  p.ln_s_b = (const float*)d_in[5];
  p.Wg     = (const float*)d_in[6];
  p.bg     = (const float*)d_in[7];
  p.ln_e_g = (const float*)d_in[8];
  p.ln_e_b = (const float*)d_in[9];
  p.Wi     = (const float*)d_in[10];
  p.bi     = (const float*)d_in[11];
  const float* Wo = (const float*)d_in[12];
  const float* bo = (const float*)d_in[13];

  char* ws = (char*)d_ws;
  float* WgT  = (float*)(ws + OF_WGT);
  float* WiT  = (float*)(ws + OF_WIT);
  float* encX = (float*)(ws + OF_ENCX);
  float* hs   = (float*)(ws + OF_HS);

  hipMemsetAsync(ws, 0, INIT_BYTES, stream);   // flags + states = 0

  hipLaunchKernelGGL(transpose_k, dim3(32, 16), dim3(32, 8), 0, stream,
                     p.Wg, WgT, 512, 1024);
  hipLaunchKernelGGL(transpose_k, dim3(32, 16), dim3(32, 8), 0, stream,
                     p.Wg + (size_t)512*1024, WgT + (size_t)1024*512, 512, 1024);
  hipLaunchKernelGGL(transpose_k, dim3(16, 32), dim3(32, 8), 0, stream,
                     p.Wi, WiT, 1024, 512);
  hipLaunchKernelGGL(transpose_k, dim3(16, 32), dim3(32, 8), 0, stream,
                     p.Wi + (size_t)1024*512, WiT + (size_t)512*1024, 1024, 512);

  hipLaunchKernelGGL(enc_gemm, dim3(DMn/128, 2048/128), dim3(256), 0, stream,
                     p.ids, p.emb, p.W_enc, p.b_enc, encX);

  hipLaunchKernelGGL(snn_scan, dim3(NWG), dim3(TPB), 86016, stream, p, ws);

  hipLaunchKernelGGL(out_gemm, dim3(Vn/128, 2048/128), dim3(256), 0, stream,
                     hs, Wo, bo, (float*)d_out);
}